// Round 10
// baseline (10500.861 us; speedup 1.0000x reference)
//
#include <hip/hip_runtime.h>
#include <math.h>

constexpr int BSZ  = 256;
constexpr int TLEN = 128;
constexpr int LLEN = 64;
constexpr int DH   = 512;
constexpr int EMBD = 128;
constexpr int ACTN = 129;
constexpr int HATT = 20;

typedef short bf16x8 __attribute__((ext_vector_type(8)));
typedef float f32x4  __attribute__((ext_vector_type(4)));

__device__ __forceinline__ short f2bf(float f) {
    unsigned u = __builtin_bit_cast(unsigned, f);
    u += 0x7fffu + ((u >> 16) & 1u);
    return (short)(u >> 16);
}
__device__ __forceinline__ float bf2f(short s) {
    unsigned u = ((unsigned)(unsigned short)s) << 16;
    return __builtin_bit_cast(float, u);
}

// ---------------------------------------------------------------------------
// Prep kernels (unchanged, proven)
// ---------------------------------------------------------------------------
__launch_bounds__(256)
__global__ void k_fold(const float* __restrict__ Wih1, const float* __restrict__ Wc,
                       float* __restrict__ W1f)
{
    __shared__ float at[64][33];
    __shared__ float bt[32][65];
    int tid = threadIdx.x;
    int tx = tid & 15, ty = tid >> 4;
    int n0 = blockIdx.x * 64, k0 = blockIdx.y * 64;
    float acc[4][4] = {};
    for (int m0 = 0; m0 < 512; m0 += 32) {
        for (int i = 0; i < 8; ++i) {
            int idx = tid + 256 * i;
            int nl = idx >> 5, ml = idx & 31;
            at[nl][ml] = Wih1[(size_t)(n0 + nl) * 512 + m0 + ml];
        }
        for (int i = 0; i < 8; ++i) {
            int idx = tid + 256 * i;
            int ml = idx >> 6, kl = idx & 63;
            bt[ml][kl] = Wc[(size_t)(m0 + ml) * 640 + k0 + kl];
        }
        __syncthreads();
        for (int m = 0; m < 32; ++m) {
            #pragma unroll
            for (int i = 0; i < 4; ++i) {
                float av = at[ty * 4 + i][m];
                #pragma unroll
                for (int j = 0; j < 4; ++j)
                    acc[i][j] += av * bt[m][tx * 4 + j];
            }
        }
        __syncthreads();
    }
    for (int i = 0; i < 4; ++i)
        for (int j = 0; j < 4; ++j)
            W1f[(size_t)(n0 + ty * 4 + i) * 640 + (k0 + tx * 4 + j)] = acc[i][j];
}

__global__ void k_pack23(const float* __restrict__ Wih, const float* __restrict__ Whh,
                         short* __restrict__ pack)
{
    int idx = blockIdx.x * 256 + threadIdx.x;       // 262144
    int lane = idx & 63;
    int ks = (idx >> 6) & 31;
    int nn = idx >> 11;
    int np = nn * 16 + (lane & 15);
    int k  = ks * 32 + ((lane >> 4) << 3);
    int n  = (np & 3) * 512 + (np >> 2);
    const float* src = (k < 512) ? (Wih + (size_t)n * 512 + k)
                                 : (Whh + (size_t)n * 512 + (k - 512));
    short* dst = pack + (size_t)idx * 8;
    #pragma unroll
    for (int i = 0; i < 8; ++i) dst[i] = f2bf(src[i]);
}

__global__ void k_pack1(const float* __restrict__ W1f, const float* __restrict__ Whh1,
                        short* __restrict__ pack)
{
    int idx = blockIdx.x * 256 + threadIdx.x;       // 294912
    int lane = idx & 63;
    int tmp = idx >> 6;
    int ks = tmp % 36;
    int nn = tmp / 36;
    int np = nn * 16 + (lane & 15);
    int k  = ks * 32 + ((lane >> 4) << 3);
    int n  = (np & 3) * 512 + (np >> 2);
    const float* src = (k < 640) ? (W1f + (size_t)n * 640 + k)
                                 : (Whh1 + (size_t)n * 512 + (k - 640));
    short* dst = pack + (size_t)idx * 8;
    #pragma unroll
    for (int i = 0; i < 8; ++i) dst[i] = f2bf(src[i]);
}

__global__ void k_packh1(const float* __restrict__ Wl1, short* __restrict__ pack)
{
    int idx = blockIdx.x * 256 + threadIdx.x;       // 65536
    int lane = idx & 63;
    int ks = (idx >> 6) & 31;
    int nn = idx >> 11;                              // <32
    int np = nn * 16 + (lane & 15);
    int k  = ks * 32 + ((lane >> 4) << 3);
    const float* src = Wl1 + (size_t)np * 1024 + k;
    short* dst = pack + (size_t)idx * 8;
    #pragma unroll
    for (int i = 0; i < 8; ++i) dst[i] = f2bf(src[i]);
}

__global__ void k_packh2(const float* __restrict__ Wl2, short* __restrict__ pack)
{
    int idx = blockIdx.x * 256 + threadIdx.x;       // 12288
    int lane = idx & 63;
    int ks = (idx >> 6) & 15;
    int nn = idx >> 10;                              // <12
    int np = nn * 16 + (lane & 15);
    int k  = ks * 32 + ((lane >> 4) << 3);
    short* dst = pack + (size_t)idx * 8;
    if (np < ACTN) {
        const float* src = Wl2 + (size_t)np * 512 + k;
        #pragma unroll
        for (int i = 0; i < 8; ++i) dst[i] = f2bf(src[i]);
    } else {
        #pragma unroll
        for (int i = 0; i < 8; ++i) dst[i] = 0;
    }
}

__global__ void k_bias(const float* __restrict__ Wih1, const float* __restrict__ bc,
                       const float* bih1, const float* bhh1,
                       const float* bih2, const float* bhh2,
                       const float* bih3, const float* bhh3,
                       float* b1p, float* b2p, float* b3p)
{
    int cp = blockIdx.x * 256 + threadIdx.x;        // 2048
    int n = (cp & 3) * 512 + (cp >> 2);
    float s = bih1[n] + bhh1[n];
    for (int m = 0; m < 512; ++m) s += Wih1[(size_t)n * 512 + m] * bc[m];
    b1p[cp] = s;
    b2p[cp] = bih2[n] + bhh2[n];
    b3p[cp] = bih3[n] + bhh3[n];
}

__global__ void k_tr(float* __restrict__ dst, const float* __restrict__ src,
                     int R, int C, int sld, int dld)
{
    int idx = blockIdx.x * 256 + threadIdx.x;
    if (idx >= R * C) return;
    int c = idx / R, r = idx - c * R;
    dst[c * dld + r] = src[r * sld + c];
}

__launch_bounds__(256)
__global__ void k_encp(const float* __restrict__ enc, const float* __restrict__ Wa1,
                       const float* __restrict__ ba1, float* __restrict__ ENCP)
{
    __shared__ float wa[HATT * 513];
    __shared__ float er[8][513];
    int b = blockIdx.x, tid = threadIdx.x;
    for (int idx = tid; idx < HATT * 512; idx += 256) {
        int h = idx >> 9, e = idx & 511;
        wa[h * 513 + e] = Wa1[h * 1024 + e];
    }
    __syncthreads();
    for (int c = 0; c < 8; ++c) {
        for (int i = 0; i < 16; ++i) {
            int idx = tid + 256 * i;
            int rr = idx >> 9, e = idx & 511;
            er[rr][e] = enc[((size_t)b * LLEN + c * 8 + rr) * 512 + e];
        }
        __syncthreads();
        if (tid < 8 * HATT) {
            int rr = tid & 7, h = tid >> 3;
            float s = 0.f;
            for (int e = 0; e < 512; ++e) s += er[rr][e] * wa[h * 513 + e];
            ENCP[((size_t)b * LLEN + c * 8 + rr) * HATT + h] = s + ba1[h];
        }
        __syncthreads();
    }
}

__global__ void k_embed(const int* __restrict__ act, const float* __restrict__ embW,
                        short* __restrict__ ET)
{
    int idx = blockIdx.x * 256 + threadIdx.x;       // 128*256*128
    int t = idx >> 15;
    int rem = idx & 32767;
    int b = rem >> 7, k = rem & 127;
    float v = 0.f;
    if (t > 0) v = embW[(size_t)act[b * TLEN + t - 1] * EMBD + k];
    ET[idx] = f2bf(v);
}

__global__ void k_encb(const float* __restrict__ enc, short* __restrict__ ENCB)
{
    int i = blockIdx.x * 256 + threadIdx.x;
    float4 v = *(const float4*)&enc[(size_t)i * 4];
    short4 o;
    o.x = f2bf(v.x); o.y = f2bf(v.y); o.z = f2bf(v.z); o.w = f2bf(v.w);
    *(short4*)&ENCB[(size_t)i * 4] = o;
}

__global__ void k_init(const float* __restrict__ eh,
                       short* h0, short* h1, short* h2, short* ctx)
{
    int i = blockIdx.x * 256 + threadIdx.x;         // 131072
    short hb = f2bf(eh[i]);
    h0[i] = hb; h1[i] = hb; h2[i] = hb; ctx[i] = 0;
}

// ---------------------------------------------------------------------------
// sc0 (L1-bypass) state loads; waitcnt bundled in-asm; sched_barrier per #18.
// ---------------------------------------------------------------------------
__device__ __forceinline__ void load_a8(const short* base,
    bf16x8& a0, bf16x8& a1, bf16x8& a2, bf16x8& a3,
    bf16x8& a4, bf16x8& a5, bf16x8& a6, bf16x8& a7)
{
    asm volatile(
        "global_load_dwordx4 %0, %8, off sc0\n\t"
        "global_load_dwordx4 %1, %8, off offset:64 sc0\n\t"
        "global_load_dwordx4 %2, %8, off offset:128 sc0\n\t"
        "global_load_dwordx4 %3, %8, off offset:192 sc0\n\t"
        "global_load_dwordx4 %4, %8, off offset:256 sc0\n\t"
        "global_load_dwordx4 %5, %8, off offset:320 sc0\n\t"
        "global_load_dwordx4 %6, %8, off offset:384 sc0\n\t"
        "global_load_dwordx4 %7, %8, off offset:448 sc0\n\t"
        "s_waitcnt vmcnt(0)"
        : "=&v"(a0), "=&v"(a1), "=&v"(a2), "=&v"(a3),
          "=&v"(a4), "=&v"(a5), "=&v"(a6), "=&v"(a7)
        : "v"(base) : "memory");
    __builtin_amdgcn_sched_barrier(0);
}

__device__ __forceinline__ void load_a4(const short* base,
    bf16x8& a0, bf16x8& a1, bf16x8& a2, bf16x8& a3)
{
    asm volatile(
        "global_load_dwordx4 %0, %4, off sc0\n\t"
        "global_load_dwordx4 %1, %4, off offset:64 sc0\n\t"
        "global_load_dwordx4 %2, %4, off offset:128 sc0\n\t"
        "global_load_dwordx4 %3, %4, off offset:192 sc0\n\t"
        "s_waitcnt vmcnt(0)"
        : "=&v"(a0), "=&v"(a1), "=&v"(a2), "=&v"(a3)
        : "v"(base) : "memory");
    __builtin_amdgcn_sched_barrier(0);
}

__device__ __forceinline__ bf16x8 load_a1(const short* p)
{
    bf16x8 r;
    asm volatile("global_load_dwordx4 %0, %1, off sc0\n\t"
                 "s_waitcnt vmcnt(0)"
                 : "=&v"(r) : "v"(p) : "memory");
    __builtin_amdgcn_sched_barrier(0);
    return r;
}

#define MFMA(af, bf, acc) \
    acc = __builtin_amdgcn_mfma_f32_16x16x32_bf16(af, bf, acc, 0, 0, 0)

// ---------------------------------------------------------------------------
// Shared LSTM epilogue: gates in gsc -> fused cell update (all 512 threads).
// ---------------------------------------------------------------------------
__device__ __forceinline__ void lstm_epilogue(
    const float* __restrict__ biasp, float* cstS, short* __restrict__ hout,
    float* gsc, int brow0, int lr, int tid)
{
    __syncthreads();
    int row = tid >> 4, j = tid & 15;
    float4 bv = *(const float4*)&biasp[(lr * 16 + j) * 4];
    float gi = gsc[row * 68 + j * 4 + 0] + bv.x;
    float gf = gsc[row * 68 + j * 4 + 1] + bv.y;
    float gg = gsc[row * 68 + j * 4 + 2] + bv.z;
    float go = gsc[row * 68 + j * 4 + 3] + bv.w;
    float c0 = cstS[tid];
    float si = 1.f / (1.f + __expf(-gi));
    float sf = 1.f / (1.f + __expf(-gf));
    float so = 1.f / (1.f + __expf(-go));
    float cn = sf * c0 + si * tanhf(gg);
    cstS[tid] = cn;
    hout[(size_t)(brow0 + row) * 512 + lr * 16 + j] = f2bf(so * tanhf(cn));
}

// ---------------------------------------------------------------------------
// LSTM1: waves 0-3 compute (W from registers + small streamed ET-part).
// ---------------------------------------------------------------------------
__device__ __forceinline__ void lstm1_reg(
    const bf16x8 (&w)[32], int wv, int lane,
    const short* __restrict__ pack1, const short* __restrict__ ET_t,
    const short* __restrict__ ctx, const short* __restrict__ h0old,
    const float* __restrict__ biasp, float* cstS, short* __restrict__ hout,
    float* gsc, int brow0, int lr, int tid)
{
    if (wv < 4) {
        const int rlane = lane & 15, kq = lane >> 4;
        const int ct = lr * 4 + wv;
        f32x4 acc0 = {}, acc1 = {};
        const short* bp = pack1 + ((size_t)(ct * 36) * 64 + lane) * 8;
        #pragma unroll
        for (int ks = 0; ks < 4; ++ks) {
            bf16x8 bf = *(const bf16x8*)(bp + ks * 512);
            bf16x8 af0 = *(const bf16x8*)(ET_t + (size_t)(brow0 + rlane) * EMBD + ks * 32 + kq * 8);
            bf16x8 af1 = *(const bf16x8*)(ET_t + (size_t)(brow0 + 16 + rlane) * EMBD + ks * 32 + kq * 8);
            MFMA(af0, bf, acc0);
            MFMA(af1, bf, acc1);
        }
        #pragma unroll
        for (int c = 0; c < 4; ++c) {
            const short* src = (c < 2) ? ctx : h0old;
            const int krel = (c & 1) * 8;
            const short* ab0 = src + (size_t)(brow0 + rlane) * 512 + krel * 32 + kq * 8;
            const short* ab1 = src + (size_t)(brow0 + 16 + rlane) * 512 + krel * 32 + kq * 8;
            bf16x8 a0, a1, a2, a3, a4, a5, a6, a7;
            load_a8(ab0, a0, a1, a2, a3, a4, a5, a6, a7);
            MFMA(a0, w[c * 8 + 0], acc0); MFMA(a1, w[c * 8 + 1], acc0);
            MFMA(a2, w[c * 8 + 2], acc0); MFMA(a3, w[c * 8 + 3], acc0);
            MFMA(a4, w[c * 8 + 4], acc0); MFMA(a5, w[c * 8 + 5], acc0);
            MFMA(a6, w[c * 8 + 6], acc0); MFMA(a7, w[c * 8 + 7], acc0);
            load_a8(ab1, a0, a1, a2, a3, a4, a5, a6, a7);
            MFMA(a0, w[c * 8 + 0], acc1); MFMA(a1, w[c * 8 + 1], acc1);
            MFMA(a2, w[c * 8 + 2], acc1); MFMA(a3, w[c * 8 + 3], acc1);
            MFMA(a4, w[c * 8 + 4], acc1); MFMA(a5, w[c * 8 + 5], acc1);
            MFMA(a6, w[c * 8 + 6], acc1); MFMA(a7, w[c * 8 + 7], acc1);
        }
        #pragma unroll
        for (int r = 0; r < 4; ++r) {
            gsc[(kq * 4 + r) * 68 + wv * 16 + rlane] = acc0[r];
            gsc[(16 + kq * 4 + r) * 68 + wv * 16 + rlane] = acc1[r];
        }
    }
    lstm_epilogue(biasp, cstS, hout, gsc, brow0, lr, tid);
}

// ---------------------------------------------------------------------------
// LSTM3: waves 4-7 compute (W from registers). A = [h1_new | h2_old].
// ---------------------------------------------------------------------------
__device__ __forceinline__ void lstm3_reg(
    const bf16x8 (&w)[32], int wv, int lane,
    const short* __restrict__ s1, const short* __restrict__ s2,
    const float* __restrict__ biasp, float* cstS, short* __restrict__ hout,
    float* gsc, int brow0, int lr, int tid)
{
    if (wv >= 4) {
        const int cw = wv - 4;
        const int rlane = lane & 15, kq = lane >> 4;
        f32x4 acc0 = {}, acc1 = {};
        #pragma unroll
        for (int c = 0; c < 4; ++c) {
            const short* src = (c < 2) ? s1 : s2;
            const int krel = (c & 1) * 8;
            const short* ab0 = src + (size_t)(brow0 + rlane) * 512 + krel * 32 + kq * 8;
            const short* ab1 = src + (size_t)(brow0 + 16 + rlane) * 512 + krel * 32 + kq * 8;
            bf16x8 a0, a1, a2, a3, a4, a5, a6, a7;
            load_a8(ab0, a0, a1, a2, a3, a4, a5, a6, a7);
            MFMA(a0, w[c * 8 + 0], acc0); MFMA(a1, w[c * 8 + 1], acc0);
            MFMA(a2, w[c * 8 + 2], acc0); MFMA(a3, w[c * 8 + 3], acc0);
            MFMA(a4, w[c * 8 + 4], acc0); MFMA(a5, w[c * 8 + 5], acc0);
            MFMA(a6, w[c * 8 + 6], acc0); MFMA(a7, w[c * 8 + 7], acc0);
            load_a8(ab1, a0, a1, a2, a3, a4, a5, a6, a7);
            MFMA(a0, w[c * 8 + 0], acc1); MFMA(a1, w[c * 8 + 1], acc1);
            MFMA(a2, w[c * 8 + 2], acc1); MFMA(a3, w[c * 8 + 3], acc1);
            MFMA(a4, w[c * 8 + 4], acc1); MFMA(a5, w[c * 8 + 5], acc1);
            MFMA(a6, w[c * 8 + 6], acc1); MFMA(a7, w[c * 8 + 7], acc1);
        }
        #pragma unroll
        for (int r = 0; r < 4; ++r) {
            gsc[(kq * 4 + r) * 68 + cw * 16 + rlane] = acc0[r];
            gsc[(16 + kq * 4 + r) * 68 + cw * 16 + rlane] = acc1[r];
        }
    }
    lstm_epilogue(biasp, cstS, hout, gsc, brow0, lr, tid);
}

// ---------------------------------------------------------------------------
// LSTM2: all 8 waves, W2 from LDS.
// ---------------------------------------------------------------------------
__device__ __forceinline__ void lstm2_lds(
    const short* wlds, const short* __restrict__ s1, const short* __restrict__ s2,
    const float* __restrict__ biasp, float* cstS, short* __restrict__ hout,
    float* gsc, int brow0, int lr, int tid)
{
    const int wave = tid >> 6, lane = tid & 63;
    const int wm = wave >> 2, wn = wave & 3;
    const int rlane = lane & 15, kq = lane >> 4;
    const int arow = brow0 + wm * 16 + rlane;
    f32x4 acc = {};
    #pragma unroll
    for (int c = 0; c < 4; ++c) {
        const int kss = c * 8;
        const short* src = (kss < 16) ? s1 : s2;
        const int krel = kss & 15;
        const short* abase = src + (size_t)arow * 512 + krel * 32 + kq * 8;
        const short* wb = wlds + ((wn * 32 + kss) * 64 + lane) * 8;
        bf16x8 b0 = *(const bf16x8*)(wb + 0 * 512);
        bf16x8 b1 = *(const bf16x8*)(wb + 1 * 512);
        bf16x8 b2 = *(const bf16x8*)(wb + 2 * 512);
        bf16x8 b3 = *(const bf16x8*)(wb + 3 * 512);
        bf16x8 b4 = *(const bf16x8*)(wb + 4 * 512);
        bf16x8 b5 = *(const bf16x8*)(wb + 5 * 512);
        bf16x8 b6 = *(const bf16x8*)(wb + 6 * 512);
        bf16x8 b7 = *(const bf16x8*)(wb + 7 * 512);
        bf16x8 a0, a1, a2, a3, a4, a5, a6, a7;
        load_a8(abase, a0, a1, a2, a3, a4, a5, a6, a7);
        MFMA(a0, b0, acc); MFMA(a1, b1, acc); MFMA(a2, b2, acc); MFMA(a3, b3, acc);
        MFMA(a4, b4, acc); MFMA(a5, b5, acc); MFMA(a6, b6, acc); MFMA(a7, b7, acc);
    }
    #pragma unroll
    for (int r = 0; r < 4; ++r)
        gsc[(wm * 16 + kq * 4 + r) * 68 + wn * 16 + rlane] = acc[r];
    lstm_epilogue(biasp, cstS, hout, gsc, brow0, lr, tid);
}

// ---------------------------------------------------------------------------
// head1: block's 16 cols, K=1024 split 4-way over wave pairs.
// ---------------------------------------------------------------------------
__device__ __forceinline__ void head1_stage(
    const short* __restrict__ ph1, const float* __restrict__ bl1,
    const short* __restrict__ h2q, const short* __restrict__ ctx,
    short* __restrict__ hidden, float* gsc, int brow0, int lr, int tid)
{
    const int wave = tid >> 6, lane = tid & 63;
    const int wm = wave & 1, kq2 = wave >> 1;
    const int rlane = lane & 15, kq = lane >> 4;
    const int arow = brow0 + wm * 16 + rlane;
    const short* src = (kq2 < 2) ? h2q : ctx;
    const int krel = (kq2 & 1) * 8;
    const short* abase = src + (size_t)arow * 512 + krel * 32 + kq * 8;
    const short* wb = ph1 + ((size_t)(lr * 32 + kq2 * 8) * 64 + lane) * 8;
    f32x4 acc = {};
    #pragma unroll
    for (int g = 0; g < 2; ++g) {
        bf16x8 b0 = *(const bf16x8*)(wb + (g * 4 + 0) * 512);
        bf16x8 b1 = *(const bf16x8*)(wb + (g * 4 + 1) * 512);
        bf16x8 b2 = *(const bf16x8*)(wb + (g * 4 + 2) * 512);
        bf16x8 b3 = *(const bf16x8*)(wb + (g * 4 + 3) * 512);
        bf16x8 a0, a1, a2, a3;
        load_a4(abase + g * 128, a0, a1, a2, a3);
        MFMA(a0, b0, acc); MFMA(a1, b1, acc); MFMA(a2, b2, acc); MFMA(a3, b3, acc);
    }
    #pragma unroll
    for (int r = 0; r < 4; ++r)
        gsc[(kq2 * 2 + wm) * 256 + (kq * 4 + r) * 16 + rlane] = acc[r];
    __syncthreads();
    {
        float s = 0.f;
        #pragma unroll
        for (int k = 0; k < 4; ++k) s += gsc[(k * 2 + (tid >> 8)) * 256 + (tid & 255)];
        int row = (tid >> 8) * 16 + ((tid >> 4) & 15);
        int col = lr * 16 + (tid & 15);
        hidden[(size_t)(brow0 + row) * 512 + col] = f2bf(fmaxf(s + bl1[col], 0.f));
    }
    __syncthreads();
}

// ---------------------------------------------------------------------------
// head2 (blocks lr 9..17): n-tile of 16 cols, K=512.
// ---------------------------------------------------------------------------
__device__ __forceinline__ void head2_stage(
    const short* __restrict__ ph2, const float* __restrict__ bl2,
    const short* __restrict__ hidden, float* __restrict__ out, int t,
    float* gsc, int brow0, int nt, int tid)
{
    const int wave = tid >> 6, lane = tid & 63;
    const int wm = wave & 1, kq4 = wave >> 1;
    const int rlane = lane & 15, kq = lane >> 4;
    const int arow = brow0 + wm * 16 + rlane;
    const short* abase = hidden + (size_t)arow * 512 + kq4 * 128 + kq * 8;
    const short* wb = ph2 + ((size_t)(nt * 16 + kq4 * 4) * 64 + lane) * 8;
    bf16x8 b0 = *(const bf16x8*)(wb + 0 * 512);
    bf16x8 b1 = *(const bf16x8*)(wb + 1 * 512);
    bf16x8 b2 = *(const bf16x8*)(wb + 2 * 512);
    bf16x8 b3 = *(const bf16x8*)(wb + 3 * 512);
    bf16x8 a0, a1, a2, a3;
    load_a4(abase, a0, a1, a2, a3);
    f32x4 acc = {};
    MFMA(a0, b0, acc); MFMA(a1, b1, acc); MFMA(a2, b2, acc); MFMA(a3, b3, acc);
    #pragma unroll
    for (int r = 0; r < 4; ++r)
        gsc[(kq4 * 2 + wm) * 256 + (kq * 4 + r) * 16 + rlane] = acc[r];
    __syncthreads();
    {
        float s = 0.f;
        #pragma unroll
        for (int k = 0; k < 4; ++k) s += gsc[(k * 2 + (tid >> 8)) * 256 + (tid & 255)];
        int row = (tid >> 8) * 16 + ((tid >> 4) & 15);
        int col = nt * 16 + (tid & 15);
        if (col < ACTN)
            out[((size_t)(brow0 + row) * TLEN + t) * ACTN + col] = s + bl2[col];
    }
}

// ---------------------------------------------------------------------------
// attention: one batch row per block; enc row held in per-thread REGISTERS.
// ---------------------------------------------------------------------------
__device__ __forceinline__ void attn_stage(
    const short* __restrict__ h2q, const bf16x8 (&encR)[8],
    const float* __restrict__ ENCP, const float* __restrict__ WaHT,
    const float* __restrict__ Wa2, const float* __restrict__ ba2v,
    short* __restrict__ ctx,
    float* h2s, float* part, float* hp, float* sl, int b, int tid)
{
    if (tid < 64) {
        bf16x8 v = load_a1(h2q + (size_t)b * 512 + tid * 8);
        #pragma unroll
        for (int i = 0; i < 8; ++i) h2s[tid * 8 + i] = bf2f(v[i]);
    }
    __syncthreads();
    if (tid < 8 * HATT) {
        int h = tid % HATT, sg = tid / HATT;
        float s = 0.f;
        for (int e = sg * 64; e < sg * 64 + 64; ++e) s += h2s[e] * WaHT[e * HATT + h];
        part[sg * HATT + h] = s;
    }
    __syncthreads();
    if (tid < HATT) {
        float s = 0.f;
        #pragma unroll
        for (int sg = 0; sg < 8; ++sg) s += part[sg * HATT + tid];
        hp[tid] = s;
    }
    __syncthreads();
    if (tid < LLEN) {
        float s = ba2v[0];
        const float* ep = ENCP + ((size_t)b * LLEN + tid) * HATT;
        #pragma unroll
        for (int h = 0; h < HATT; ++h)
            s += fmaxf(ep[h] + hp[h], 0.f) * Wa2[h];
        float v = tanhf(s);
        float m = v;
        for (int o = 32; o; o >>= 1) m = fmaxf(m, __shfl_xor(m, o));
        float e = __expf(v - m);
        float ss = e;
        for (int o = 32; o; o >>= 1) ss += __shfl_xor(ss, o);
        sl[tid] = e / ss;
    }
    __syncthreads();
    {
        float a = 0.f;
        #pragma unroll
        for (int i = 0; i < 8; ++i)
            #pragma unroll
            for (int j = 0; j < 8; ++j)
                a += sl[i * 8 + j] * bf2f(encR[i][j]);
        ctx[(size_t)b * 512 + tid] = f2bf(a);
    }
    __syncthreads();
}

// ---------------------------------------------------------------------------
// Persistent megakernel. __launch_bounds__(512, 2): 2 waves/EU -> 256-VGPR
// budget so wreg[32] (128 VGPR) + encR[8] (32 VGPR) truly live in registers
// (r7/r8 silently spilled them to scratch at the default 128 cap — that
// scratch traffic was the 4-5 GB FETCH).
// Barrier: r8's PROVEN flag-array (relaxed agent atomics, per-block line,
// 64-lane poll) — r9's asm barrier rewrite is reverted (timeout suspect).
// ---------------------------------------------------------------------------
__launch_bounds__(512, 2)
__global__ void k_mega(
    const short* __restrict__ pack1, const short* __restrict__ pack2,
    const short* __restrict__ pack3, const short* __restrict__ ph1,
    const short* __restrict__ ph2,
    const float* __restrict__ b1p, const float* __restrict__ b2p,
    const float* __restrict__ b3p, const float* __restrict__ bl1,
    const float* __restrict__ bl2,
    const short* __restrict__ ET, const short* __restrict__ ENCB,
    const float* __restrict__ ENCP, const float* __restrict__ WaHT,
    const float* __restrict__ Wa2, const float* __restrict__ ba2v,
    const float* __restrict__ enc_c,
    short* __restrict__ h0a, short* __restrict__ h0b,
    short* __restrict__ h1a, short* __restrict__ h1b,
    short* __restrict__ h2a, short* __restrict__ h2b,
    short* __restrict__ ctx, short* __restrict__ hidden,
    int* __restrict__ cnt, unsigned* __restrict__ bar,
    float* __restrict__ out)
{
    __shared__ __align__(16) short wlds[65536];   // 128 KB: W2 slice
    __shared__ float gsc[2176];
    __shared__ float cst[3 * 512];
    __shared__ float h2s[512];
    __shared__ float part[8 * HATT];
    __shared__ float hp[HATT];
    __shared__ float sl[LLEN];
    __shared__ int sinfo[2];

    const int tid = threadIdx.x;
    const int wv = tid >> 6, lane = tid & 63;

    // --- runtime XCD registration (agent scope, one-time) ---
    int xcd_reg;
    asm volatile("s_getreg_b32 %0, hwreg(HW_REG_XCC_ID)" : "=s"(xcd_reg));
    if (tid == 0) {
        sinfo[0] = xcd_reg;
        sinfo[1] = __hip_atomic_fetch_add(&cnt[xcd_reg], 1,
                                          __ATOMIC_RELAXED, __HIP_MEMORY_SCOPE_AGENT);
    }
    __syncthreads();
    const int myx = sinfo[0], lr = sinfo[1];
    const int brow0 = myx * 32;

    // --- park W2 slice in LDS (one-time) ---
    {
        const bf16x8* s2v = (const bf16x8*)(pack2 + (size_t)lr * 65536);
        bf16x8* dst = (bf16x8*)wlds;
        for (int i = tid; i < 8192; i += 512)
            dst[i] = __builtin_nontemporal_load(&s2v[i]);
    }
    // --- park W1 (waves 0-3) / W3 (waves 4-7) in REGISTERS ---
    bf16x8 wreg[32];
    {
        const short* wsrc = (wv < 4)
            ? pack1 + ((size_t)((lr * 4 + wv) * 36 + 4) * 64 + lane) * 8
            : pack3 + ((size_t)((lr * 4 + (wv - 4)) * 32) * 64 + lane) * 8;
        #pragma unroll
        for (int i = 0; i < 32; ++i)
            wreg[i] = *(const bf16x8*)(wsrc + (size_t)i * 512);
    }
    // --- park this block's enc row in REGISTERS (col tid across l) ---
    bf16x8 encR[8];
    {
        const short* ebase = ENCB + ((size_t)(brow0 + lr) * LLEN) * 512 + tid;
        #pragma unroll
        for (int i = 0; i < 8; ++i) {
            bf16x8 v;
            #pragma unroll
            for (int j = 0; j < 8; ++j) v[j] = ebase[(size_t)(i * 8 + j) * 512];
            encR[i] = v;
        }
    }
    // --- c-state init ---
    {
        int row = tid >> 4, j = tid & 15;
        float cv = enc_c[(size_t)(brow0 + row) * 512 + lr * 16 + j];
        cst[tid] = cv; cst[512 + tid] = cv; cst[1024 + tid] = cv;
    }
    __syncthreads();

    // --- flag-array barrier (r8-proven): per-block line, 64-lane poll ---
    unsigned gen = 0;
    unsigned* myslot = &bar[(myx * 32 + lr) * 16];
    unsigned* xslots = &bar[(size_t)myx * 32 * 16];
    auto gbar = [&]() {
        ++gen;
        asm volatile("s_waitcnt vmcnt(0)" ::: "memory");
        __syncthreads();
        if (tid == 0)
            __hip_atomic_store(myslot, gen, __ATOMIC_RELAXED,
                               __HIP_MEMORY_SCOPE_AGENT);
        if (tid < 64) {
            for (;;) {
                unsigned v = 0xFFFFFFFFu;
                if (tid < 32)
                    v = __hip_atomic_load(&xslots[tid * 16], __ATOMIC_RELAXED,
                                          __HIP_MEMORY_SCOPE_AGENT);
                if (__all(v >= gen)) break;
                __builtin_amdgcn_s_sleep(2);
            }
        }
        __syncthreads();
    };

    short* h0p[2] = { h0a, h0b };
    short* h1p[2] = { h1a, h1b };
    short* h2p[2] = { h2a, h2b };
    const int b_att = brow0 + lr;

    for (int t = 0; t < TLEN; ++t) {
        int p = t & 1, q = p ^ 1;
        // P1: LSTM1 (waves 0-3, W1 in regs)
        lstm1_reg(wreg, wv, lane, pack1, ET + (size_t)t * BSZ * EMBD,
                  ctx, h0p[p], b1p, cst, h0p[q], gsc, brow0, lr, tid);
        gbar();
        // P2: LSTM2 (all waves, W2 in LDS)
        lstm2_lds(wlds, h0p[q], h1p[p], b2p, cst + 512, h1p[q],
                  gsc, brow0, lr, tid);
        gbar();
        // P3: LSTM3 (waves 4-7, W3 in regs)
        lstm3_reg(wreg, wv, lane, h1p[q], h2p[p], b3p, cst + 1024, h2p[q],
                  gsc, brow0, lr, tid);
        gbar();
        // P4: attention + head2(t-1) on blocks 9..17
        attn_stage(h2p[q], encR, ENCP, WaHT, Wa2, ba2v, ctx,
                   h2s, part, hp, sl, b_att, tid);
        if (t > 0 && lr >= 9 && lr < 18)
            head2_stage(ph2, bl2, hidden, out, t - 1, gsc, brow0, lr - 9, tid);
        gbar();
        // P5: head1 -> hidden(t)  (synced via bars of t+1)
        head1_stage(ph1, bl1, h2p[q], ctx, hidden, gsc, brow0, lr, tid);
    }
    gbar();
    if (lr >= 9 && lr < 18)
        head2_stage(ph2, bl2, hidden, out, TLEN - 1, gsc, brow0, lr - 9, tid);
}

// ---------------------------------------------------------------------------
extern "C" void kernel_launch(void* const* d_in, const int* in_sizes, int n_in,
                              void* d_out, int out_size, void* d_ws, size_t ws_size,
                              hipStream_t stream)
{
    const int*   act   = (const int*)d_in[0];
    const float* enc   = (const float*)d_in[1];
    const float* enc_h = (const float*)d_in[2];
    const float* enc_c = (const float*)d_in[3];
    const float* embW  = (const float*)d_in[4];
    const float* Wc    = (const float*)d_in[5];
    const float* bc    = (const float*)d_in[6];
    const float* Wih1  = (const float*)d_in[7];
    const float* Whh1  = (const float*)d_in[8];
    const float* bih1  = (const float*)d_in[9];
    const float* bhh1  = (const float*)d_in[10];
    const float* Wih2  = (const float*)d_in[11];
    const float* Whh2  = (const float*)d_in[12];
    const float* bih2  = (const float*)d_in[13];
    const float* bhh2  = (const float*)d_in[14];
    const float* Wih3  = (const float*)d_in[15];
    const float* Whh3  = (const float*)d_in[16];
    const float* bih3  = (const float*)d_in[17];
    const float* bhh3  = (const float*)d_in[18];
    const float* Wa1   = (const float*)d_in[19];
    const float* ba1   = (const float*)d_in[20];
    const float* Wa2   = (const float*)d_in[21];
    const float* ba2   = (const float*)d_in[22];
    const float* Wl1   = (const float*)d_in[23];
    const float* bl1   = (const float*)d_in[24];
    const float* Wl2   = (const float*)d_in[25];
    const float* bl2   = (const float*)d_in[26];
    float* out = (float*)d_out;

    char* cur = (char*)d_ws;
    auto alloc = [&](size_t bytes) {
        char* p = cur;
        cur += (bytes + 255) & ~(size_t)255;
        return p;
    };
    int* cnt = (int*)alloc(64);
    unsigned* bar = (unsigned*)alloc(8 * 32 * 16 * 4);   // 16 KB flag slots
    short* pack1  = (short*)alloc((size_t)2048 * 1152 * 2);
    short* pack2  = (short*)alloc((size_t)2048 * 1024 * 2);
    short* pack3  = (short*)alloc((size_t)2048 * 1024 * 2);
    short* packh1 = (short*)alloc((size_t)512 * 1024 * 2);
    short* packh2 = (short*)alloc((size_t)192 * 512 * 2);
    short* ENCB   = (short*)alloc((size_t)BSZ * LLEN * 512 * 2);  // 16.8 MB
    float* W1f    = (float*)ENCB;                                  // prep alias
    float* b1p    = (float*)alloc(2048 * 4);
    float* b2p    = (float*)alloc(2048 * 4);
    float* b3p    = (float*)alloc(2048 * 4);
    float* WaHT   = (float*)alloc(512 * HATT * 4);
    float* ENCP   = (float*)alloc((size_t)BSZ * LLEN * HATT * 4);
    short* ET     = (short*)alloc((size_t)TLEN * BSZ * EMBD * 2);
    const size_t SB = (size_t)BSZ * DH;
    short* h0a = (short*)alloc(SB * 2); short* h0b = (short*)alloc(SB * 2);
    short* h1a = (short*)alloc(SB * 2); short* h1b = (short*)alloc(SB * 2);
    short* h2a = (short*)alloc(SB * 2); short* h2b = (short*)alloc(SB * 2);
    short* ctx    = (short*)alloc(SB * 2);
    short* hidden = (short*)alloc(SB * 2);

    // ---- prep ----
    hipMemsetAsync(cnt, 0, 64, stream);
    hipMemsetAsync(bar, 0, 8 * 32 * 16 * 4, stream);
    k_fold<<<dim3(32, 10), 256, 0, stream>>>(Wih1, Wc, W1f);
    k_pack1<<<1152, 256, 0, stream>>>(W1f, Whh1, pack1);
    k_encb<<<8192, 256, 0, stream>>>(enc, ENCB);      // overwrites W1f region
    k_pack23<<<1024, 256, 0, stream>>>(Wih2, Whh2, pack2);
    k_pack23<<<1024, 256, 0, stream>>>(Wih3, Whh3, pack3);
    k_packh1<<<256, 256, 0, stream>>>(Wl1, packh1);
    k_packh2<<<48, 256, 0, stream>>>(Wl2, packh2);
    k_bias<<<8, 256, 0, stream>>>(Wih1, bc, bih1, bhh1, bih2, bhh2, bih3, bhh3,
                                  b1p, b2p, b3p);
    k_tr<<<(HATT * 512 + 255) / 256, 256, 0, stream>>>(WaHT, Wa1 + 512, HATT, 512, 1024, HATT);
    k_encp<<<BSZ, 256, 0, stream>>>(enc, Wa1, ba1, ENCP);
    k_embed<<<(TLEN * BSZ * EMBD) / 256, 256, 0, stream>>>(act, embW, ET);
    k_init<<<512, 256, 0, stream>>>(enc_h, h0a, h1a, h2a, ctx);

    // ---- persistent recurrent megakernel ----
    k_mega<<<256, 512, 0, stream>>>(
        pack1, pack2, pack3, packh1, packh2,
        b1p, b2p, b3p, bl1, bl2,
        ET, ENCB, ENCP, WaHT, Wa2, ba2,
        enc_c,
        h0a, h0b, h1a, h1b, h2a, h2b,
        ctx, hidden, cnt, bar, out);
}

// Round 11
// 9113.146 us; speedup vs baseline: 1.1523x; 1.1523x over previous
//
#include <hip/hip_runtime.h>
#include <math.h>

constexpr int BSZ  = 256;
constexpr int TLEN = 128;
constexpr int LLEN = 64;
constexpr int DH   = 512;
constexpr int EMBD = 128;
constexpr int ACTN = 129;
constexpr int HATT = 20;

typedef short bf16x8 __attribute__((ext_vector_type(8)));
typedef float f32x4  __attribute__((ext_vector_type(4)));

__device__ __forceinline__ short f2bf(float f) {
    unsigned u = __builtin_bit_cast(unsigned, f);
    u += 0x7fffu + ((u >> 16) & 1u);
    return (short)(u >> 16);
}
__device__ __forceinline__ float bf2f(short s) {
    unsigned u = ((unsigned)(unsigned short)s) << 16;
    return __builtin_bit_cast(float, u);
}

// ---------------------------------------------------------------------------
// Prep kernels (unchanged, proven)
// ---------------------------------------------------------------------------
__launch_bounds__(256)
__global__ void k_fold(const float* __restrict__ Wih1, const float* __restrict__ Wc,
                       float* __restrict__ W1f)
{
    __shared__ float at[64][33];
    __shared__ float bt[32][65];
    int tid = threadIdx.x;
    int tx = tid & 15, ty = tid >> 4;
    int n0 = blockIdx.x * 64, k0 = blockIdx.y * 64;
    float acc[4][4] = {};
    for (int m0 = 0; m0 < 512; m0 += 32) {
        for (int i = 0; i < 8; ++i) {
            int idx = tid + 256 * i;
            int nl = idx >> 5, ml = idx & 31;
            at[nl][ml] = Wih1[(size_t)(n0 + nl) * 512 + m0 + ml];
        }
        for (int i = 0; i < 8; ++i) {
            int idx = tid + 256 * i;
            int ml = idx >> 6, kl = idx & 63;
            bt[ml][kl] = Wc[(size_t)(m0 + ml) * 640 + k0 + kl];
        }
        __syncthreads();
        for (int m = 0; m < 32; ++m) {
            #pragma unroll
            for (int i = 0; i < 4; ++i) {
                float av = at[ty * 4 + i][m];
                #pragma unroll
                for (int j = 0; j < 4; ++j)
                    acc[i][j] += av * bt[m][tx * 4 + j];
            }
        }
        __syncthreads();
    }
    for (int i = 0; i < 4; ++i)
        for (int j = 0; j < 4; ++j)
            W1f[(size_t)(n0 + ty * 4 + i) * 640 + (k0 + tx * 4 + j)] = acc[i][j];
}

__global__ void k_pack23(const float* __restrict__ Wih, const float* __restrict__ Whh,
                         short* __restrict__ pack)
{
    int idx = blockIdx.x * 256 + threadIdx.x;       // 262144
    int lane = idx & 63;
    int ks = (idx >> 6) & 31;
    int nn = idx >> 11;
    int np = nn * 16 + (lane & 15);
    int k  = ks * 32 + ((lane >> 4) << 3);
    int n  = (np & 3) * 512 + (np >> 2);
    const float* src = (k < 512) ? (Wih + (size_t)n * 512 + k)
                                 : (Whh + (size_t)n * 512 + (k - 512));
    short* dst = pack + (size_t)idx * 8;
    #pragma unroll
    for (int i = 0; i < 8; ++i) dst[i] = f2bf(src[i]);
}

__global__ void k_pack1(const float* __restrict__ W1f, const float* __restrict__ Whh1,
                        short* __restrict__ pack)
{
    int idx = blockIdx.x * 256 + threadIdx.x;       // 294912
    int lane = idx & 63;
    int tmp = idx >> 6;
    int ks = tmp % 36;
    int nn = tmp / 36;
    int np = nn * 16 + (lane & 15);
    int k  = ks * 32 + ((lane >> 4) << 3);
    int n  = (np & 3) * 512 + (np >> 2);
    const float* src = (k < 640) ? (W1f + (size_t)n * 640 + k)
                                 : (Whh1 + (size_t)n * 512 + (k - 640));
    short* dst = pack + (size_t)idx * 8;
    #pragma unroll
    for (int i = 0; i < 8; ++i) dst[i] = f2bf(src[i]);
}

__global__ void k_packh1(const float* __restrict__ Wl1, short* __restrict__ pack)
{
    int idx = blockIdx.x * 256 + threadIdx.x;       // 65536
    int lane = idx & 63;
    int ks = (idx >> 6) & 31;
    int nn = idx >> 11;                              // <32
    int np = nn * 16 + (lane & 15);
    int k  = ks * 32 + ((lane >> 4) << 3);
    const float* src = Wl1 + (size_t)np * 1024 + k;
    short* dst = pack + (size_t)idx * 8;
    #pragma unroll
    for (int i = 0; i < 8; ++i) dst[i] = f2bf(src[i]);
}

__global__ void k_packh2(const float* __restrict__ Wl2, short* __restrict__ pack)
{
    int idx = blockIdx.x * 256 + threadIdx.x;       // 12288
    int lane = idx & 63;
    int ks = (idx >> 6) & 15;
    int nn = idx >> 10;                              // <12
    int np = nn * 16 + (lane & 15);
    int k  = ks * 32 + ((lane >> 4) << 3);
    short* dst = pack + (size_t)idx * 8;
    if (np < ACTN) {
        const float* src = Wl2 + (size_t)np * 512 + k;
        #pragma unroll
        for (int i = 0; i < 8; ++i) dst[i] = f2bf(src[i]);
    } else {
        #pragma unroll
        for (int i = 0; i < 8; ++i) dst[i] = 0;
    }
}

__global__ void k_bias(const float* __restrict__ Wih1, const float* __restrict__ bc,
                       const float* bih1, const float* bhh1,
                       const float* bih2, const float* bhh2,
                       const float* bih3, const float* bhh3,
                       float* b1p, float* b2p, float* b3p)
{
    int cp = blockIdx.x * 256 + threadIdx.x;        // 2048
    int n = (cp & 3) * 512 + (cp >> 2);
    float s = bih1[n] + bhh1[n];
    for (int m = 0; m < 512; ++m) s += Wih1[(size_t)n * 512 + m] * bc[m];
    b1p[cp] = s;
    b2p[cp] = bih2[n] + bhh2[n];
    b3p[cp] = bih3[n] + bhh3[n];
}

__global__ void k_tr(float* __restrict__ dst, const float* __restrict__ src,
                     int R, int C, int sld, int dld)
{
    int idx = blockIdx.x * 256 + threadIdx.x;
    if (idx >= R * C) return;
    int c = idx / R, r = idx - c * R;
    dst[c * dld + r] = src[r * sld + c];
}

__launch_bounds__(256)
__global__ void k_encp(const float* __restrict__ enc, const float* __restrict__ Wa1,
                       const float* __restrict__ ba1, float* __restrict__ ENCP)
{
    __shared__ float wa[HATT * 513];
    __shared__ float er[8][513];
    int b = blockIdx.x, tid = threadIdx.x;
    for (int idx = tid; idx < HATT * 512; idx += 256) {
        int h = idx >> 9, e = idx & 511;
        wa[h * 513 + e] = Wa1[h * 1024 + e];
    }
    __syncthreads();
    for (int c = 0; c < 8; ++c) {
        for (int i = 0; i < 16; ++i) {
            int idx = tid + 256 * i;
            int rr = idx >> 9, e = idx & 511;
            er[rr][e] = enc[((size_t)b * LLEN + c * 8 + rr) * 512 + e];
        }
        __syncthreads();
        if (tid < 8 * HATT) {
            int rr = tid & 7, h = tid >> 3;
            float s = 0.f;
            for (int e = 0; e < 512; ++e) s += er[rr][e] * wa[h * 513 + e];
            ENCP[((size_t)b * LLEN + c * 8 + rr) * HATT + h] = s + ba1[h];
        }
        __syncthreads();
    }
}

__global__ void k_embed(const int* __restrict__ act, const float* __restrict__ embW,
                        short* __restrict__ ET)
{
    int idx = blockIdx.x * 256 + threadIdx.x;       // 128*256*128
    int t = idx >> 15;
    int rem = idx & 32767;
    int b = rem >> 7, k = rem & 127;
    float v = 0.f;
    if (t > 0) v = embW[(size_t)act[b * TLEN + t - 1] * EMBD + k];
    ET[idx] = f2bf(v);
}

__global__ void k_encb(const float* __restrict__ enc, short* __restrict__ ENCB)
{
    int i = blockIdx.x * 256 + threadIdx.x;
    float4 v = *(const float4*)&enc[(size_t)i * 4];
    short4 o;
    o.x = f2bf(v.x); o.y = f2bf(v.y); o.z = f2bf(v.z); o.w = f2bf(v.w);
    *(short4*)&ENCB[(size_t)i * 4] = o;
}

__global__ void k_init(const float* __restrict__ eh,
                       short* h0, short* h1, short* h2, short* ctx)
{
    int i = blockIdx.x * 256 + threadIdx.x;         // 131072
    short hb = f2bf(eh[i]);
    h0[i] = hb; h1[i] = hb; h2[i] = hb; ctx[i] = 0;
}

// ---------------------------------------------------------------------------
// State loads: PLAIN (L1+L2 cached). Correctness vs stale L1 comes from the
// buffer_inv (vector-L1 invalidate) issued at every barrier exit — writers'
// stores are already in the shared XCD L2 (write-through L1 + vmcnt(0) at
// barrier entry), so post-inv plain loads observe them as L2 hits.
// ---------------------------------------------------------------------------
__device__ __forceinline__ void load_a8(const short* base,
    bf16x8& a0, bf16x8& a1, bf16x8& a2, bf16x8& a3,
    bf16x8& a4, bf16x8& a5, bf16x8& a6, bf16x8& a7)
{
    a0 = *(const bf16x8*)(base +   0);
    a1 = *(const bf16x8*)(base +  32);
    a2 = *(const bf16x8*)(base +  64);
    a3 = *(const bf16x8*)(base +  96);
    a4 = *(const bf16x8*)(base + 128);
    a5 = *(const bf16x8*)(base + 160);
    a6 = *(const bf16x8*)(base + 192);
    a7 = *(const bf16x8*)(base + 224);
}

__device__ __forceinline__ void load_a4(const short* base,
    bf16x8& a0, bf16x8& a1, bf16x8& a2, bf16x8& a3)
{
    a0 = *(const bf16x8*)(base +  0);
    a1 = *(const bf16x8*)(base + 32);
    a2 = *(const bf16x8*)(base + 64);
    a3 = *(const bf16x8*)(base + 96);
}

__device__ __forceinline__ bf16x8 load_a1(const short* p)
{
    return *(const bf16x8*)p;
}

#define MFMA(af, bf, acc) \
    acc = __builtin_amdgcn_mfma_f32_16x16x32_bf16(af, bf, acc, 0, 0, 0)

// ---------------------------------------------------------------------------
// Shared LSTM epilogue: gates in gsc -> fused cell update (all 512 threads).
// ---------------------------------------------------------------------------
__device__ __forceinline__ void lstm_epilogue(
    const float* __restrict__ biasp, float* cstS, short* __restrict__ hout,
    float* gsc, int brow0, int lr, int tid)
{
    __syncthreads();
    int row = tid >> 4, j = tid & 15;
    float4 bv = *(const float4*)&biasp[(lr * 16 + j) * 4];
    float gi = gsc[row * 68 + j * 4 + 0] + bv.x;
    float gf = gsc[row * 68 + j * 4 + 1] + bv.y;
    float gg = gsc[row * 68 + j * 4 + 2] + bv.z;
    float go = gsc[row * 68 + j * 4 + 3] + bv.w;
    float c0 = cstS[tid];
    float si = 1.f / (1.f + __expf(-gi));
    float sf = 1.f / (1.f + __expf(-gf));
    float so = 1.f / (1.f + __expf(-go));
    float cn = sf * c0 + si * tanhf(gg);
    cstS[tid] = cn;
    hout[(size_t)(brow0 + row) * 512 + lr * 16 + j] = f2bf(so * tanhf(cn));
}

// ---------------------------------------------------------------------------
// LSTM1: waves 0-3 compute (W from registers + small streamed ET-part).
// ---------------------------------------------------------------------------
__device__ __forceinline__ void lstm1_reg(
    const bf16x8 (&w)[32], int wv, int lane,
    const short* __restrict__ pack1, const short* __restrict__ ET_t,
    const short* __restrict__ ctx, const short* __restrict__ h0old,
    const float* __restrict__ biasp, float* cstS, short* __restrict__ hout,
    float* gsc, int brow0, int lr, int tid)
{
    if (wv < 4) {
        const int rlane = lane & 15, kq = lane >> 4;
        const int ct = lr * 4 + wv;
        f32x4 acc0 = {}, acc1 = {};
        const short* bp = pack1 + ((size_t)(ct * 36) * 64 + lane) * 8;
        #pragma unroll
        for (int ks = 0; ks < 4; ++ks) {
            bf16x8 bf = *(const bf16x8*)(bp + ks * 512);
            bf16x8 af0 = *(const bf16x8*)(ET_t + (size_t)(brow0 + rlane) * EMBD + ks * 32 + kq * 8);
            bf16x8 af1 = *(const bf16x8*)(ET_t + (size_t)(brow0 + 16 + rlane) * EMBD + ks * 32 + kq * 8);
            MFMA(af0, bf, acc0);
            MFMA(af1, bf, acc1);
        }
        #pragma unroll
        for (int c = 0; c < 4; ++c) {
            const short* src = (c < 2) ? ctx : h0old;
            const int krel = (c & 1) * 8;
            const short* ab0 = src + (size_t)(brow0 + rlane) * 512 + krel * 32 + kq * 8;
            const short* ab1 = src + (size_t)(brow0 + 16 + rlane) * 512 + krel * 32 + kq * 8;
            bf16x8 a0, a1, a2, a3, a4, a5, a6, a7;
            load_a8(ab0, a0, a1, a2, a3, a4, a5, a6, a7);
            MFMA(a0, w[c * 8 + 0], acc0); MFMA(a1, w[c * 8 + 1], acc0);
            MFMA(a2, w[c * 8 + 2], acc0); MFMA(a3, w[c * 8 + 3], acc0);
            MFMA(a4, w[c * 8 + 4], acc0); MFMA(a5, w[c * 8 + 5], acc0);
            MFMA(a6, w[c * 8 + 6], acc0); MFMA(a7, w[c * 8 + 7], acc0);
            load_a8(ab1, a0, a1, a2, a3, a4, a5, a6, a7);
            MFMA(a0, w[c * 8 + 0], acc1); MFMA(a1, w[c * 8 + 1], acc1);
            MFMA(a2, w[c * 8 + 2], acc1); MFMA(a3, w[c * 8 + 3], acc1);
            MFMA(a4, w[c * 8 + 4], acc1); MFMA(a5, w[c * 8 + 5], acc1);
            MFMA(a6, w[c * 8 + 6], acc1); MFMA(a7, w[c * 8 + 7], acc1);
        }
        #pragma unroll
        for (int r = 0; r < 4; ++r) {
            gsc[(kq * 4 + r) * 68 + wv * 16 + rlane] = acc0[r];
            gsc[(16 + kq * 4 + r) * 68 + wv * 16 + rlane] = acc1[r];
        }
    }
    lstm_epilogue(biasp, cstS, hout, gsc, brow0, lr, tid);
}

// ---------------------------------------------------------------------------
// LSTM3: waves 4-7 compute (W from registers). A = [h1_new | h2_old].
// ---------------------------------------------------------------------------
__device__ __forceinline__ void lstm3_reg(
    const bf16x8 (&w)[32], int wv, int lane,
    const short* __restrict__ s1, const short* __restrict__ s2,
    const float* __restrict__ biasp, float* cstS, short* __restrict__ hout,
    float* gsc, int brow0, int lr, int tid)
{
    if (wv >= 4) {
        const int cw = wv - 4;
        const int rlane = lane & 15, kq = lane >> 4;
        f32x4 acc0 = {}, acc1 = {};
        #pragma unroll
        for (int c = 0; c < 4; ++c) {
            const short* src = (c < 2) ? s1 : s2;
            const int krel = (c & 1) * 8;
            const short* ab0 = src + (size_t)(brow0 + rlane) * 512 + krel * 32 + kq * 8;
            const short* ab1 = src + (size_t)(brow0 + 16 + rlane) * 512 + krel * 32 + kq * 8;
            bf16x8 a0, a1, a2, a3, a4, a5, a6, a7;
            load_a8(ab0, a0, a1, a2, a3, a4, a5, a6, a7);
            MFMA(a0, w[c * 8 + 0], acc0); MFMA(a1, w[c * 8 + 1], acc0);
            MFMA(a2, w[c * 8 + 2], acc0); MFMA(a3, w[c * 8 + 3], acc0);
            MFMA(a4, w[c * 8 + 4], acc0); MFMA(a5, w[c * 8 + 5], acc0);
            MFMA(a6, w[c * 8 + 6], acc0); MFMA(a7, w[c * 8 + 7], acc0);
            load_a8(ab1, a0, a1, a2, a3, a4, a5, a6, a7);
            MFMA(a0, w[c * 8 + 0], acc1); MFMA(a1, w[c * 8 + 1], acc1);
            MFMA(a2, w[c * 8 + 2], acc1); MFMA(a3, w[c * 8 + 3], acc1);
            MFMA(a4, w[c * 8 + 4], acc1); MFMA(a5, w[c * 8 + 5], acc1);
            MFMA(a6, w[c * 8 + 6], acc1); MFMA(a7, w[c * 8 + 7], acc1);
        }
        #pragma unroll
        for (int r = 0; r < 4; ++r) {
            gsc[(kq * 4 + r) * 68 + cw * 16 + rlane] = acc0[r];
            gsc[(16 + kq * 4 + r) * 68 + cw * 16 + rlane] = acc1[r];
        }
    }
    lstm_epilogue(biasp, cstS, hout, gsc, brow0, lr, tid);
}

// ---------------------------------------------------------------------------
// LSTM2: all 8 waves, W2 from LDS.
// ---------------------------------------------------------------------------
__device__ __forceinline__ void lstm2_lds(
    const short* wlds, const short* __restrict__ s1, const short* __restrict__ s2,
    const float* __restrict__ biasp, float* cstS, short* __restrict__ hout,
    float* gsc, int brow0, int lr, int tid)
{
    const int wave = tid >> 6, lane = tid & 63;
    const int wm = wave >> 2, wn = wave & 3;
    const int rlane = lane & 15, kq = lane >> 4;
    const int arow = brow0 + wm * 16 + rlane;
    f32x4 acc = {};
    #pragma unroll
    for (int c = 0; c < 4; ++c) {
        const int kss = c * 8;
        const short* src = (kss < 16) ? s1 : s2;
        const int krel = kss & 15;
        const short* abase = src + (size_t)arow * 512 + krel * 32 + kq * 8;
        const short* wb = wlds + ((wn * 32 + kss) * 64 + lane) * 8;
        bf16x8 b0 = *(const bf16x8*)(wb + 0 * 512);
        bf16x8 b1 = *(const bf16x8*)(wb + 1 * 512);
        bf16x8 b2 = *(const bf16x8*)(wb + 2 * 512);
        bf16x8 b3 = *(const bf16x8*)(wb + 3 * 512);
        bf16x8 b4 = *(const bf16x8*)(wb + 4 * 512);
        bf16x8 b5 = *(const bf16x8*)(wb + 5 * 512);
        bf16x8 b6 = *(const bf16x8*)(wb + 6 * 512);
        bf16x8 b7 = *(const bf16x8*)(wb + 7 * 512);
        bf16x8 a0, a1, a2, a3, a4, a5, a6, a7;
        load_a8(abase, a0, a1, a2, a3, a4, a5, a6, a7);
        MFMA(a0, b0, acc); MFMA(a1, b1, acc); MFMA(a2, b2, acc); MFMA(a3, b3, acc);
        MFMA(a4, b4, acc); MFMA(a5, b5, acc); MFMA(a6, b6, acc); MFMA(a7, b7, acc);
    }
    #pragma unroll
    for (int r = 0; r < 4; ++r)
        gsc[(wm * 16 + kq * 4 + r) * 68 + wn * 16 + rlane] = acc[r];
    lstm_epilogue(biasp, cstS, hout, gsc, brow0, lr, tid);
}

// ---------------------------------------------------------------------------
// head1: block's 16 cols, K=1024 split 4-way over wave pairs.
// ---------------------------------------------------------------------------
__device__ __forceinline__ void head1_stage(
    const short* __restrict__ ph1, const float* __restrict__ bl1,
    const short* __restrict__ h2q, const short* __restrict__ ctx,
    short* __restrict__ hidden, float* gsc, int brow0, int lr, int tid)
{
    const int wave = tid >> 6, lane = tid & 63;
    const int wm = wave & 1, kq2 = wave >> 1;
    const int rlane = lane & 15, kq = lane >> 4;
    const int arow = brow0 + wm * 16 + rlane;
    const short* src = (kq2 < 2) ? h2q : ctx;
    const int krel = (kq2 & 1) * 8;
    const short* abase = src + (size_t)arow * 512 + krel * 32 + kq * 8;
    const short* wb = ph1 + ((size_t)(lr * 32 + kq2 * 8) * 64 + lane) * 8;
    f32x4 acc = {};
    #pragma unroll
    for (int g = 0; g < 2; ++g) {
        bf16x8 b0 = *(const bf16x8*)(wb + (g * 4 + 0) * 512);
        bf16x8 b1 = *(const bf16x8*)(wb + (g * 4 + 1) * 512);
        bf16x8 b2 = *(const bf16x8*)(wb + (g * 4 + 2) * 512);
        bf16x8 b3 = *(const bf16x8*)(wb + (g * 4 + 3) * 512);
        bf16x8 a0, a1, a2, a3;
        load_a4(abase + g * 128, a0, a1, a2, a3);
        MFMA(a0, b0, acc); MFMA(a1, b1, acc); MFMA(a2, b2, acc); MFMA(a3, b3, acc);
    }
    #pragma unroll
    for (int r = 0; r < 4; ++r)
        gsc[(kq2 * 2 + wm) * 256 + (kq * 4 + r) * 16 + rlane] = acc[r];
    __syncthreads();
    {
        float s = 0.f;
        #pragma unroll
        for (int k = 0; k < 4; ++k) s += gsc[(k * 2 + (tid >> 8)) * 256 + (tid & 255)];
        int row = (tid >> 8) * 16 + ((tid >> 4) & 15);
        int col = lr * 16 + (tid & 15);
        hidden[(size_t)(brow0 + row) * 512 + col] = f2bf(fmaxf(s + bl1[col], 0.f));
    }
    __syncthreads();
}

// ---------------------------------------------------------------------------
// head2 (blocks lr 9..17): n-tile of 16 cols, K=512.
// ---------------------------------------------------------------------------
__device__ __forceinline__ void head2_stage(
    const short* __restrict__ ph2, const float* __restrict__ bl2,
    const short* __restrict__ hidden, float* __restrict__ out, int t,
    float* gsc, int brow0, int nt, int tid)
{
    const int wave = tid >> 6, lane = tid & 63;
    const int wm = wave & 1, kq4 = wave >> 1;
    const int rlane = lane & 15, kq = lane >> 4;
    const int arow = brow0 + wm * 16 + rlane;
    const short* abase = hidden + (size_t)arow * 512 + kq4 * 128 + kq * 8;
    const short* wb = ph2 + ((size_t)(nt * 16 + kq4 * 4) * 64 + lane) * 8;
    bf16x8 b0 = *(const bf16x8*)(wb + 0 * 512);
    bf16x8 b1 = *(const bf16x8*)(wb + 1 * 512);
    bf16x8 b2 = *(const bf16x8*)(wb + 2 * 512);
    bf16x8 b3 = *(const bf16x8*)(wb + 3 * 512);
    bf16x8 a0, a1, a2, a3;
    load_a4(abase, a0, a1, a2, a3);
    f32x4 acc = {};
    MFMA(a0, b0, acc); MFMA(a1, b1, acc); MFMA(a2, b2, acc); MFMA(a3, b3, acc);
    #pragma unroll
    for (int r = 0; r < 4; ++r)
        gsc[(kq4 * 2 + wm) * 256 + (kq * 4 + r) * 16 + rlane] = acc[r];
    __syncthreads();
    {
        float s = 0.f;
        #pragma unroll
        for (int k = 0; k < 4; ++k) s += gsc[(k * 2 + (tid >> 8)) * 256 + (tid & 255)];
        int row = (tid >> 8) * 16 + ((tid >> 4) & 15);
        int col = nt * 16 + (tid & 15);
        if (col < ACTN)
            out[((size_t)(brow0 + row) * TLEN + t) * ACTN + col] = s + bl2[col];
    }
}

// ---------------------------------------------------------------------------
// attention: one batch row per block; enc row held in per-thread REGISTERS.
// ---------------------------------------------------------------------------
__device__ __forceinline__ void attn_stage(
    const short* __restrict__ h2q, const bf16x8 (&encR)[8],
    const float* __restrict__ ENCP, const float* __restrict__ WaHT,
    const float* __restrict__ Wa2, const float* __restrict__ ba2v,
    short* __restrict__ ctx,
    float* h2s, float* part, float* hp, float* sl, int b, int tid)
{
    if (tid < 64) {
        bf16x8 v = load_a1(h2q + (size_t)b * 512 + tid * 8);
        #pragma unroll
        for (int i = 0; i < 8; ++i) h2s[tid * 8 + i] = bf2f(v[i]);
    }
    __syncthreads();
    if (tid < 8 * HATT) {
        int h = tid % HATT, sg = tid / HATT;
        float s = 0.f;
        for (int e = sg * 64; e < sg * 64 + 64; ++e) s += h2s[e] * WaHT[e * HATT + h];
        part[sg * HATT + h] = s;
    }
    __syncthreads();
    if (tid < HATT) {
        float s = 0.f;
        #pragma unroll
        for (int sg = 0; sg < 8; ++sg) s += part[sg * HATT + tid];
        hp[tid] = s;
    }
    __syncthreads();
    if (tid < LLEN) {
        float s = ba2v[0];
        const float* ep = ENCP + ((size_t)b * LLEN + tid) * HATT;
        #pragma unroll
        for (int h = 0; h < HATT; ++h)
            s += fmaxf(ep[h] + hp[h], 0.f) * Wa2[h];
        float v = tanhf(s);
        float m = v;
        for (int o = 32; o; o >>= 1) m = fmaxf(m, __shfl_xor(m, o));
        float e = __expf(v - m);
        float ss = e;
        for (int o = 32; o; o >>= 1) ss += __shfl_xor(ss, o);
        sl[tid] = e / ss;
    }
    __syncthreads();
    {
        float a = 0.f;
        #pragma unroll
        for (int i = 0; i < 8; ++i)
            #pragma unroll
            for (int j = 0; j < 8; ++j)
                a += sl[i * 8 + j] * bf2f(encR[i][j]);
        ctx[(size_t)b * 512 + tid] = f2bf(a);
    }
    __syncthreads();
}

// ---------------------------------------------------------------------------
// Persistent megakernel. Change vs r10 (single semantic change, A/B-clean):
// state loads are PLAIN (L2-cacheable) instead of sc0 inline-asm, with a
// vector-L1 invalidate (buffer_inv) at every barrier exit. Theory: sc0 loads
// are agent-scope on gfx950 -> served past L2 (MALL) -> the 5 GB FETCH and
// the latency chain. Plain loads + per-phase L1 inv keep state exchange
// entirely within the XCD's L2 (writers' stores are there at vmcnt(0):
// vector L1 is write-through).
// ---------------------------------------------------------------------------
__launch_bounds__(512, 2)
__global__ void k_mega(
    const short* __restrict__ pack1, const short* __restrict__ pack2,
    const short* __restrict__ pack3, const short* __restrict__ ph1,
    const short* __restrict__ ph2,
    const float* __restrict__ b1p, const float* __restrict__ b2p,
    const float* __restrict__ b3p, const float* __restrict__ bl1,
    const float* __restrict__ bl2,
    const short* __restrict__ ET, const short* __restrict__ ENCB,
    const float* __restrict__ ENCP, const float* __restrict__ WaHT,
    const float* __restrict__ Wa2, const float* __restrict__ ba2v,
    const float* __restrict__ enc_c,
    short* __restrict__ h0a, short* __restrict__ h0b,
    short* __restrict__ h1a, short* __restrict__ h1b,
    short* __restrict__ h2a, short* __restrict__ h2b,
    short* __restrict__ ctx, short* __restrict__ hidden,
    int* __restrict__ cnt, unsigned* __restrict__ bar,
    float* __restrict__ out)
{
    __shared__ __align__(16) short wlds[65536];   // 128 KB: W2 slice
    __shared__ float gsc[2176];
    __shared__ float cst[3 * 512];
    __shared__ float h2s[512];
    __shared__ float part[8 * HATT];
    __shared__ float hp[HATT];
    __shared__ float sl[LLEN];
    __shared__ int sinfo[2];

    const int tid = threadIdx.x;
    const int wv = tid >> 6, lane = tid & 63;

    // --- runtime XCD registration (agent scope, one-time) ---
    int xcd_reg;
    asm volatile("s_getreg_b32 %0, hwreg(HW_REG_XCC_ID)" : "=s"(xcd_reg));
    if (tid == 0) {
        sinfo[0] = xcd_reg;
        sinfo[1] = __hip_atomic_fetch_add(&cnt[xcd_reg], 1,
                                          __ATOMIC_RELAXED, __HIP_MEMORY_SCOPE_AGENT);
    }
    __syncthreads();
    const int myx = sinfo[0], lr = sinfo[1];
    const int brow0 = myx * 32;

    // --- park W2 slice in LDS (one-time) ---
    {
        const bf16x8* s2v = (const bf16x8*)(pack2 + (size_t)lr * 65536);
        bf16x8* dst = (bf16x8*)wlds;
        for (int i = tid; i < 8192; i += 512)
            dst[i] = __builtin_nontemporal_load(&s2v[i]);
    }
    // --- park W1 (waves 0-3) / W3 (waves 4-7) in REGISTERS/AGPRs ---
    bf16x8 wreg[32];
    {
        const short* wsrc = (wv < 4)
            ? pack1 + ((size_t)((lr * 4 + wv) * 36 + 4) * 64 + lane) * 8
            : pack3 + ((size_t)((lr * 4 + (wv - 4)) * 32) * 64 + lane) * 8;
        #pragma unroll
        for (int i = 0; i < 32; ++i)
            wreg[i] = *(const bf16x8*)(wsrc + (size_t)i * 512);
    }
    // --- park this block's enc row in REGISTERS (col tid across l) ---
    bf16x8 encR[8];
    {
        const short* ebase = ENCB + ((size_t)(brow0 + lr) * LLEN) * 512 + tid;
        #pragma unroll
        for (int i = 0; i < 8; ++i) {
            bf16x8 v;
            #pragma unroll
            for (int j = 0; j < 8; ++j) v[j] = ebase[(size_t)(i * 8 + j) * 512];
            encR[i] = v;
        }
    }
    // --- c-state init ---
    {
        int row = tid >> 4, j = tid & 15;
        float cv = enc_c[(size_t)(brow0 + row) * 512 + lr * 16 + j];
        cst[tid] = cv; cst[512 + tid] = cv; cst[1024 + tid] = cv;
    }
    __syncthreads();

    // --- flag-array barrier (r8-proven) + L1 invalidate on exit ---
    unsigned gen = 0;
    unsigned* myslot = &bar[(myx * 32 + lr) * 16];
    unsigned* xslots = &bar[(size_t)myx * 32 * 16];
    auto gbar = [&]() {
        ++gen;
        asm volatile("s_waitcnt vmcnt(0)" ::: "memory");  // stores acked at L2
        __syncthreads();
        if (tid == 0)
            __hip_atomic_store(myslot, gen, __ATOMIC_RELAXED,
                               __HIP_MEMORY_SCOPE_AGENT);
        if (tid < 64) {
            for (;;) {
                unsigned v = 0xFFFFFFFFu;
                if (tid < 32)
                    v = __hip_atomic_load(&xslots[tid * 16], __ATOMIC_RELAXED,
                                          __HIP_MEMORY_SCOPE_AGENT);
                if (__all(v >= gen)) break;
                __builtin_amdgcn_s_sleep(2);
            }
        }
        __syncthreads();
        // invalidate vector L1 (per-CU) so plain state loads see the XCD-L2
        // values written by other blocks this step. L2 untouched.
        asm volatile("buffer_inv" ::: "memory");
    };

    short* h0p[2] = { h0a, h0b };
    short* h1p[2] = { h1a, h1b };
    short* h2p[2] = { h2a, h2b };
    const int b_att = brow0 + lr;

    for (int t = 0; t < TLEN; ++t) {
        int p = t & 1, q = p ^ 1;
        // P1: LSTM1 (waves 0-3, W1 in regs)
        lstm1_reg(wreg, wv, lane, pack1, ET + (size_t)t * BSZ * EMBD,
                  ctx, h0p[p], b1p, cst, h0p[q], gsc, brow0, lr, tid);
        gbar();
        // P2: LSTM2 (all waves, W2 in LDS)
        lstm2_lds(wlds, h0p[q], h1p[p], b2p, cst + 512, h1p[q],
                  gsc, brow0, lr, tid);
        gbar();
        // P3: LSTM3 (waves 4-7, W3 in regs)
        lstm3_reg(wreg, wv, lane, h1p[q], h2p[p], b3p, cst + 1024, h2p[q],
                  gsc, brow0, lr, tid);
        gbar();
        // P4: attention + head2(t-1) on blocks 9..17
        attn_stage(h2p[q], encR, ENCP, WaHT, Wa2, ba2v, ctx,
                   h2s, part, hp, sl, b_att, tid);
        if (t > 0 && lr >= 9 && lr < 18)
            head2_stage(ph2, bl2, hidden, out, t - 1, gsc, brow0, lr - 9, tid);
        gbar();
        // P5: head1 -> hidden(t)  (synced via bars of t+1)
        head1_stage(ph1, bl1, h2p[q], ctx, hidden, gsc, brow0, lr, tid);
    }
    gbar();
    if (lr >= 9 && lr < 18)
        head2_stage(ph2, bl2, hidden, out, TLEN - 1, gsc, brow0, lr - 9, tid);
}

// ---------------------------------------------------------------------------
extern "C" void kernel_launch(void* const* d_in, const int* in_sizes, int n_in,
                              void* d_out, int out_size, void* d_ws, size_t ws_size,
                              hipStream_t stream)
{
    const int*   act   = (const int*)d_in[0];
    const float* enc   = (const float*)d_in[1];
    const float* enc_h = (const float*)d_in[2];
    const float* enc_c = (const float*)d_in[3];
    const float* embW  = (const float*)d_in[4];
    const float* Wc    = (const float*)d_in[5];
    const float* bc    = (const float*)d_in[6];
    const float* Wih1  = (const float*)d_in[7];
    const float* Whh1  = (const float*)d_in[8];
    const float* bih1  = (const float*)d_in[9];
    const float* bhh1  = (const float*)d_in[10];
    const float* Wih2  = (const float*)d_in[11];
    const float* Whh2  = (const float*)d_in[12];
    const float* bih2  = (const float*)d_in[13];
    const float* bhh2  = (const float*)d_in[14];
    const float* Wih3  = (const float*)d_in[15];
    const float* Whh3  = (const float*)d_in[16];
    const float* bih3  = (const float*)d_in[17];
    const float* bhh3  = (const float*)d_in[18];
    const float* Wa1   = (const float*)d_in[19];
    const float* ba1   = (const float*)d_in[20];
    const float* Wa2   = (const float*)d_in[21];
    const float* ba2   = (const float*)d_in[22];
    const float* Wl1   = (const float*)d_in[23];
    const float* bl1   = (const float*)d_in[24];
    const float* Wl2   = (const float*)d_in[25];
    const float* bl2   = (const float*)d_in[26];
    float* out = (float*)d_out;

    char* cur = (char*)d_ws;
    auto alloc = [&](size_t bytes) {
        char* p = cur;
        cur += (bytes + 255) & ~(size_t)255;
        return p;
    };
    int* cnt = (int*)alloc(64);
    unsigned* bar = (unsigned*)alloc(8 * 32 * 16 * 4);   // 16 KB flag slots
    short* pack1  = (short*)alloc((size_t)2048 * 1152 * 2);
    short* pack2  = (short*)alloc((size_t)2048 * 1024 * 2);
    short* pack3  = (short*)alloc((size_t)2048 * 1024 * 2);
    short* packh1 = (short*)alloc((size_t)512 * 1024 * 2);
    short* packh2 = (short*)alloc((size_t)192 * 512 * 2);
    short* ENCB   = (short*)alloc((size_t)BSZ * LLEN * 512 * 2);  // 16.8 MB
    float* W1f    = (float*)ENCB;                                  // prep alias
    float* b1p    = (float*)alloc(2048 * 4);
    float* b2p    = (float*)alloc(2048 * 4);
    float* b3p    = (float*)alloc(2048 * 4);
    float* WaHT   = (float*)alloc(512 * HATT * 4);
    float* ENCP   = (float*)alloc((size_t)BSZ * LLEN * HATT * 4);
    short* ET     = (short*)alloc((size_t)TLEN * BSZ * EMBD * 2);
    const size_t SB = (size_t)BSZ * DH;
    short* h0a = (short*)alloc(SB * 2); short* h0b = (short*)alloc(SB * 2);
    short* h1a = (short*)alloc(SB * 2); short* h1b = (short*)alloc(SB * 2);
    short* h2a = (short*)alloc(SB * 2); short* h2b = (short*)alloc(SB * 2);
    short* ctx    = (short*)alloc(SB * 2);
    short* hidden = (short*)alloc(SB * 2);

    // ---- prep ----
    hipMemsetAsync(cnt, 0, 64, stream);
    hipMemsetAsync(bar, 0, 8 * 32 * 16 * 4, stream);
    k_fold<<<dim3(32, 10), 256, 0, stream>>>(Wih1, Wc, W1f);
    k_pack1<<<1152, 256, 0, stream>>>(W1f, Whh1, pack1);
    k_encb<<<8192, 256, 0, stream>>>(enc, ENCB);      // overwrites W1f region
    k_pack23<<<1024, 256, 0, stream>>>(Wih2, Whh2, pack2);
    k_pack23<<<1024, 256, 0, stream>>>(Wih3, Whh3, pack3);
    k_packh1<<<256, 256, 0, stream>>>(Wl1, packh1);
    k_packh2<<<48, 256, 0, stream>>>(Wl2, packh2);
    k_bias<<<8, 256, 0, stream>>>(Wih1, bc, bih1, bhh1, bih2, bhh2, bih3, bhh3,
                                  b1p, b2p, b3p);
    k_tr<<<(HATT * 512 + 255) / 256, 256, 0, stream>>>(WaHT, Wa1 + 512, HATT, 512, 1024, HATT);
    k_encp<<<BSZ, 256, 0, stream>>>(enc, Wa1, ba1, ENCP);
    k_embed<<<(TLEN * BSZ * EMBD) / 256, 256, 0, stream>>>(act, embW, ET);
    k_init<<<512, 256, 0, stream>>>(enc_h, h0a, h1a, h2a, ctx);

    // ---- persistent recurrent megakernel ----
    k_mega<<<256, 512, 0, stream>>>(
        pack1, pack2, pack3, packh1, packh2,
        b1p, b2p, b3p, bl1, bl2,
        ET, ENCB, ENCP, WaHT, Wa2, ba2,
        enc_c,
        h0a, h0b, h1a, h1b, h2a, h2b,
        ctx, hidden, cnt, bar, out);
}

// Round 13
// 9040.444 us; speedup vs baseline: 1.1615x; 1.0080x over previous
//
#include <hip/hip_runtime.h>
#include <math.h>

constexpr int BSZ  = 256;
constexpr int TLEN = 128;
constexpr int LLEN = 64;
constexpr int DH   = 512;
constexpr int EMBD = 128;
constexpr int ACTN = 129;
constexpr int HATT = 20;

typedef short bf16x8 __attribute__((ext_vector_type(8)));
typedef float f32x4  __attribute__((ext_vector_type(4)));

__device__ __forceinline__ short f2bf(float f) {
    unsigned u = __builtin_bit_cast(unsigned, f);
    u += 0x7fffu + ((u >> 16) & 1u);
    return (short)(u >> 16);
}
__device__ __forceinline__ float bf2f(short s) {
    unsigned u = ((unsigned)(unsigned short)s) << 16;
    return __builtin_bit_cast(float, u);
}

// ---------------------------------------------------------------------------
// Prep kernels (unchanged, proven)
// ---------------------------------------------------------------------------
__launch_bounds__(256)
__global__ void k_fold(const float* __restrict__ Wih1, const float* __restrict__ Wc,
                       float* __restrict__ W1f)
{
    __shared__ float at[64][33];
    __shared__ float bt[32][65];
    int tid = threadIdx.x;
    int tx = tid & 15, ty = tid >> 4;
    int n0 = blockIdx.x * 64, k0 = blockIdx.y * 64;
    float acc[4][4] = {};
    for (int m0 = 0; m0 < 512; m0 += 32) {
        for (int i = 0; i < 8; ++i) {
            int idx = tid + 256 * i;
            int nl = idx >> 5, ml = idx & 31;
            at[nl][ml] = Wih1[(size_t)(n0 + nl) * 512 + m0 + ml];
        }
        for (int i = 0; i < 8; ++i) {
            int idx = tid + 256 * i;
            int ml = idx >> 6, kl = idx & 63;
            bt[ml][kl] = Wc[(size_t)(m0 + ml) * 640 + k0 + kl];
        }
        __syncthreads();
        for (int m = 0; m < 32; ++m) {
            #pragma unroll
            for (int i = 0; i < 4; ++i) {
                float av = at[ty * 4 + i][m];
                #pragma unroll
                for (int j = 0; j < 4; ++j)
                    acc[i][j] += av * bt[m][tx * 4 + j];
            }
        }
        __syncthreads();
    }
    for (int i = 0; i < 4; ++i)
        for (int j = 0; j < 4; ++j)
            W1f[(size_t)(n0 + ty * 4 + i) * 640 + (k0 + tx * 4 + j)] = acc[i][j];
}

__global__ void k_pack23(const float* __restrict__ Wih, const float* __restrict__ Whh,
                         short* __restrict__ pack)
{
    int idx = blockIdx.x * 256 + threadIdx.x;       // 262144
    int lane = idx & 63;
    int ks = (idx >> 6) & 31;
    int nn = idx >> 11;
    int np = nn * 16 + (lane & 15);
    int k  = ks * 32 + ((lane >> 4) << 3);
    int n  = (np & 3) * 512 + (np >> 2);
    const float* src = (k < 512) ? (Wih + (size_t)n * 512 + k)
                                 : (Whh + (size_t)n * 512 + (k - 512));
    short* dst = pack + (size_t)idx * 8;
    #pragma unroll
    for (int i = 0; i < 8; ++i) dst[i] = f2bf(src[i]);
}

__global__ void k_pack1(const float* __restrict__ W1f, const float* __restrict__ Whh1,
                        short* __restrict__ pack)
{
    int idx = blockIdx.x * 256 + threadIdx.x;       // 294912
    int lane = idx & 63;
    int tmp = idx >> 6;
    int ks = tmp % 36;
    int nn = tmp / 36;
    int np = nn * 16 + (lane & 15);
    int k  = ks * 32 + ((lane >> 4) << 3);
    int n  = (np & 3) * 512 + (np >> 2);
    const float* src = (k < 640) ? (W1f + (size_t)n * 640 + k)
                                 : (Whh1 + (size_t)n * 512 + (k - 640));
    short* dst = pack + (size_t)idx * 8;
    #pragma unroll
    for (int i = 0; i < 8; ++i) dst[i] = f2bf(src[i]);
}

__global__ void k_packh1(const float* __restrict__ Wl1, short* __restrict__ pack)
{
    int idx = blockIdx.x * 256 + threadIdx.x;       // 65536
    int lane = idx & 63;
    int ks = (idx >> 6) & 31;
    int nn = idx >> 11;                              // <32
    int np = nn * 16 + (lane & 15);
    int k  = ks * 32 + ((lane >> 4) << 3);
    const float* src = Wl1 + (size_t)np * 1024 + k;
    short* dst = pack + (size_t)idx * 8;
    #pragma unroll
    for (int i = 0; i < 8; ++i) dst[i] = f2bf(src[i]);
}

__global__ void k_packh2(const float* __restrict__ Wl2, short* __restrict__ pack)
{
    int idx = blockIdx.x * 256 + threadIdx.x;       // 12288
    int lane = idx & 63;
    int ks = (idx >> 6) & 15;
    int nn = idx >> 10;                              // <12
    int np = nn * 16 + (lane & 15);
    int k  = ks * 32 + ((lane >> 4) << 3);
    short* dst = pack + (size_t)idx * 8;
    if (np < ACTN) {
        const float* src = Wl2 + (size_t)np * 512 + k;
        #pragma unroll
        for (int i = 0; i < 8; ++i) dst[i] = f2bf(src[i]);
    } else {
        #pragma unroll
        for (int i = 0; i < 8; ++i) dst[i] = 0;
    }
}

__global__ void k_bias(const float* __restrict__ Wih1, const float* __restrict__ bc,
                       const float* bih1, const float* bhh1,
                       const float* bih2, const float* bhh2,
                       const float* bih3, const float* bhh3,
                       float* b1p, float* b2p, float* b3p)
{
    int cp = blockIdx.x * 256 + threadIdx.x;        // 2048
    int n = (cp & 3) * 512 + (cp >> 2);
    float s = bih1[n] + bhh1[n];
    for (int m = 0; m < 512; ++m) s += Wih1[(size_t)n * 512 + m] * bc[m];
    b1p[cp] = s;
    b2p[cp] = bih2[n] + bhh2[n];
    b3p[cp] = bih3[n] + bhh3[n];
}

__global__ void k_tr(float* __restrict__ dst, const float* __restrict__ src,
                     int R, int C, int sld, int dld)
{
    int idx = blockIdx.x * 256 + threadIdx.x;
    if (idx >= R * C) return;
    int c = idx / R, r = idx - c * R;
    dst[c * dld + r] = src[r * sld + c];
}

__launch_bounds__(256)
__global__ void k_encp(const float* __restrict__ enc, const float* __restrict__ Wa1,
                       const float* __restrict__ ba1, float* __restrict__ ENCP)
{
    __shared__ float wa[HATT * 513];
    __shared__ float er[8][513];
    int b = blockIdx.x, tid = threadIdx.x;
    for (int idx = tid; idx < HATT * 512; idx += 256) {
        int h = idx >> 9, e = idx & 511;
        wa[h * 513 + e] = Wa1[h * 1024 + e];
    }
    __syncthreads();
    for (int c = 0; c < 8; ++c) {
        for (int i = 0; i < 16; ++i) {
            int idx = tid + 256 * i;
            int rr = idx >> 9, e = idx & 511;
            er[rr][e] = enc[((size_t)b * LLEN + c * 8 + rr) * 512 + e];
        }
        __syncthreads();
        if (tid < 8 * HATT) {
            int rr = tid & 7, h = tid >> 3;
            float s = 0.f;
            for (int e = 0; e < 512; ++e) s += er[rr][e] * wa[h * 513 + e];
            ENCP[((size_t)b * LLEN + c * 8 + rr) * HATT + h] = s + ba1[h];
        }
        __syncthreads();
    }
}

__global__ void k_embed(const int* __restrict__ act, const float* __restrict__ embW,
                        short* __restrict__ ET)
{
    int idx = blockIdx.x * 256 + threadIdx.x;       // 128*256*128
    int t = idx >> 15;
    int rem = idx & 32767;
    int b = rem >> 7, k = rem & 127;
    float v = 0.f;
    if (t > 0) v = embW[(size_t)act[b * TLEN + t - 1] * EMBD + k];
    ET[idx] = f2bf(v);
}

__global__ void k_encb(const float* __restrict__ enc, short* __restrict__ ENCB)
{
    int i = blockIdx.x * 256 + threadIdx.x;
    float4 v = *(const float4*)&enc[(size_t)i * 4];
    short4 o;
    o.x = f2bf(v.x); o.y = f2bf(v.y); o.z = f2bf(v.z); o.w = f2bf(v.w);
    *(short4*)&ENCB[(size_t)i * 4] = o;
}

__global__ void k_init(const float* __restrict__ eh,
                       short* h0, short* h1, short* h2, short* ctx)
{
    int i = blockIdx.x * 256 + threadIdx.x;         // 131072
    short hb = f2bf(eh[i]);
    h0[i] = hb; h1[i] = hb; h2[i] = hb; ctx[i] = 0;
}

// ---------------------------------------------------------------------------
// State loads: PLAIN (L1+L2 cached); freshness from buffer_inv at barrier
// exit. Proven correct by r11 (absmax unchanged over the 128-step chain).
// ---------------------------------------------------------------------------
__device__ __forceinline__ void load_a8(const short* base,
    bf16x8& a0, bf16x8& a1, bf16x8& a2, bf16x8& a3,
    bf16x8& a4, bf16x8& a5, bf16x8& a6, bf16x8& a7)
{
    a0 = *(const bf16x8*)(base +   0);
    a1 = *(const bf16x8*)(base +  32);
    a2 = *(const bf16x8*)(base +  64);
    a3 = *(const bf16x8*)(base +  96);
    a4 = *(const bf16x8*)(base + 128);
    a5 = *(const bf16x8*)(base + 160);
    a6 = *(const bf16x8*)(base + 192);
    a7 = *(const bf16x8*)(base + 224);
}

__device__ __forceinline__ void load_a4(const short* base,
    bf16x8& a0, bf16x8& a1, bf16x8& a2, bf16x8& a3)
{
    a0 = *(const bf16x8*)(base +  0);
    a1 = *(const bf16x8*)(base + 32);
    a2 = *(const bf16x8*)(base + 64);
    a3 = *(const bf16x8*)(base + 96);
}

__device__ __forceinline__ bf16x8 load_a1(const short* p)
{
    return *(const bf16x8*)p;
}

#define MFMA(af, bf, acc) \
    acc = __builtin_amdgcn_mfma_f32_16x16x32_bf16(af, bf, acc, 0, 0, 0)

// ---------------------------------------------------------------------------
// Shared LSTM epilogue: gates in gsc -> fused cell update (all 512 threads).
// ---------------------------------------------------------------------------
__device__ __forceinline__ void lstm_epilogue(
    const float* __restrict__ biasp, float* cstS, short* __restrict__ hout,
    float* gsc, int brow0, int lr, int tid)
{
    __syncthreads();
    int row = tid >> 4, j = tid & 15;
    float4 bv = *(const float4*)&biasp[(lr * 16 + j) * 4];
    float gi = gsc[row * 68 + j * 4 + 0] + bv.x;
    float gf = gsc[row * 68 + j * 4 + 1] + bv.y;
    float gg = gsc[row * 68 + j * 4 + 2] + bv.z;
    float go = gsc[row * 68 + j * 4 + 3] + bv.w;
    float c0 = cstS[tid];
    float si = 1.f / (1.f + __expf(-gi));
    float sf = 1.f / (1.f + __expf(-gf));
    float so = 1.f / (1.f + __expf(-go));
    float cn = sf * c0 + si * tanhf(gg);
    cstS[tid] = cn;
    hout[(size_t)(brow0 + row) * 512 + lr * 16 + j] = f2bf(so * tanhf(cn));
}

// ---------------------------------------------------------------------------
// LSTM1: waves 0-3 compute (W from registers + small streamed ET-part).
// ---------------------------------------------------------------------------
__device__ __forceinline__ void lstm1_reg(
    const bf16x8 (&w)[32], int wv, int lane,
    const short* __restrict__ pack1, const short* __restrict__ ET_t,
    const short* __restrict__ ctx, const short* __restrict__ h0old,
    const float* __restrict__ biasp, float* cstS, short* __restrict__ hout,
    float* gsc, int brow0, int lr, int tid)
{
    if (wv < 4) {
        const int rlane = lane & 15, kq = lane >> 4;
        const int ct = lr * 4 + wv;
        f32x4 acc0 = {}, acc1 = {};
        const short* bp = pack1 + ((size_t)(ct * 36) * 64 + lane) * 8;
        #pragma unroll
        for (int ks = 0; ks < 4; ++ks) {
            bf16x8 bf = *(const bf16x8*)(bp + ks * 512);
            bf16x8 af0 = *(const bf16x8*)(ET_t + (size_t)(brow0 + rlane) * EMBD + ks * 32 + kq * 8);
            bf16x8 af1 = *(const bf16x8*)(ET_t + (size_t)(brow0 + 16 + rlane) * EMBD + ks * 32 + kq * 8);
            MFMA(af0, bf, acc0);
            MFMA(af1, bf, acc1);
        }
        #pragma unroll
        for (int c = 0; c < 4; ++c) {
            const short* src = (c < 2) ? ctx : h0old;
            const int krel = (c & 1) * 8;
            const short* ab0 = src + (size_t)(brow0 + rlane) * 512 + krel * 32 + kq * 8;
            const short* ab1 = src + (size_t)(brow0 + 16 + rlane) * 512 + krel * 32 + kq * 8;
            bf16x8 a0, a1, a2, a3, a4, a5, a6, a7;
            load_a8(ab0, a0, a1, a2, a3, a4, a5, a6, a7);
            MFMA(a0, w[c * 8 + 0], acc0); MFMA(a1, w[c * 8 + 1], acc0);
            MFMA(a2, w[c * 8 + 2], acc0); MFMA(a3, w[c * 8 + 3], acc0);
            MFMA(a4, w[c * 8 + 4], acc0); MFMA(a5, w[c * 8 + 5], acc0);
            MFMA(a6, w[c * 8 + 6], acc0); MFMA(a7, w[c * 8 + 7], acc0);
            load_a8(ab1, a0, a1, a2, a3, a4, a5, a6, a7);
            MFMA(a0, w[c * 8 + 0], acc1); MFMA(a1, w[c * 8 + 1], acc1);
            MFMA(a2, w[c * 8 + 2], acc1); MFMA(a3, w[c * 8 + 3], acc1);
            MFMA(a4, w[c * 8 + 4], acc1); MFMA(a5, w[c * 8 + 5], acc1);
            MFMA(a6, w[c * 8 + 6], acc1); MFMA(a7, w[c * 8 + 7], acc1);
        }
        #pragma unroll
        for (int r = 0; r < 4; ++r) {
            gsc[(kq * 4 + r) * 68 + wv * 16 + rlane] = acc0[r];
            gsc[(16 + kq * 4 + r) * 68 + wv * 16 + rlane] = acc1[r];
        }
    }
    lstm_epilogue(biasp, cstS, hout, gsc, brow0, lr, tid);
}

// ---------------------------------------------------------------------------
// LSTM3: waves 4-7 compute (W from registers). A = [h1_new | h2_old].
// ---------------------------------------------------------------------------
__device__ __forceinline__ void lstm3_reg(
    const bf16x8 (&w)[32], int wv, int lane,
    const short* __restrict__ s1, const short* __restrict__ s2,
    const float* __restrict__ biasp, float* cstS, short* __restrict__ hout,
    float* gsc, int brow0, int lr, int tid)
{
    if (wv >= 4) {
        const int cw = wv - 4;
        const int rlane = lane & 15, kq = lane >> 4;
        f32x4 acc0 = {}, acc1 = {};
        #pragma unroll
        for (int c = 0; c < 4; ++c) {
            const short* src = (c < 2) ? s1 : s2;
            const int krel = (c & 1) * 8;
            const short* ab0 = src + (size_t)(brow0 + rlane) * 512 + krel * 32 + kq * 8;
            const short* ab1 = src + (size_t)(brow0 + 16 + rlane) * 512 + krel * 32 + kq * 8;
            bf16x8 a0, a1, a2, a3, a4, a5, a6, a7;
            load_a8(ab0, a0, a1, a2, a3, a4, a5, a6, a7);
            MFMA(a0, w[c * 8 + 0], acc0); MFMA(a1, w[c * 8 + 1], acc0);
            MFMA(a2, w[c * 8 + 2], acc0); MFMA(a3, w[c * 8 + 3], acc0);
            MFMA(a4, w[c * 8 + 4], acc0); MFMA(a5, w[c * 8 + 5], acc0);
            MFMA(a6, w[c * 8 + 6], acc0); MFMA(a7, w[c * 8 + 7], acc0);
            load_a8(ab1, a0, a1, a2, a3, a4, a5, a6, a7);
            MFMA(a0, w[c * 8 + 0], acc1); MFMA(a1, w[c * 8 + 1], acc1);
            MFMA(a2, w[c * 8 + 2], acc1); MFMA(a3, w[c * 8 + 3], acc1);
            MFMA(a4, w[c * 8 + 4], acc1); MFMA(a5, w[c * 8 + 5], acc1);
            MFMA(a6, w[c * 8 + 6], acc1); MFMA(a7, w[c * 8 + 7], acc1);
        }
        #pragma unroll
        for (int r = 0; r < 4; ++r) {
            gsc[(kq * 4 + r) * 68 + cw * 16 + rlane] = acc0[r];
            gsc[(16 + kq * 4 + r) * 68 + cw * 16 + rlane] = acc1[r];
        }
    }
    lstm_epilogue(biasp, cstS, hout, gsc, brow0, lr, tid);
}

// ---------------------------------------------------------------------------
// LSTM2: all 8 waves, W2 from LDS.
// ---------------------------------------------------------------------------
__device__ __forceinline__ void lstm2_lds(
    const short* wlds, const short* __restrict__ s1, const short* __restrict__ s2,
    const float* __restrict__ biasp, float* cstS, short* __restrict__ hout,
    float* gsc, int brow0, int lr, int tid)
{
    const int wave = tid >> 6, lane = tid & 63;
    const int wm = wave >> 2, wn = wave & 3;
    const int rlane = lane & 15, kq = lane >> 4;
    const int arow = brow0 + wm * 16 + rlane;
    f32x4 acc = {};
    #pragma unroll
    for (int c = 0; c < 4; ++c) {
        const int kss = c * 8;
        const short* src = (kss < 16) ? s1 : s2;
        const int krel = kss & 15;
        const short* abase = src + (size_t)arow * 512 + krel * 32 + kq * 8;
        const short* wb = wlds + ((wn * 32 + kss) * 64 + lane) * 8;
        bf16x8 b0 = *(const bf16x8*)(wb + 0 * 512);
        bf16x8 b1 = *(const bf16x8*)(wb + 1 * 512);
        bf16x8 b2 = *(const bf16x8*)(wb + 2 * 512);
        bf16x8 b3 = *(const bf16x8*)(wb + 3 * 512);
        bf16x8 b4 = *(const bf16x8*)(wb + 4 * 512);
        bf16x8 b5 = *(const bf16x8*)(wb + 5 * 512);
        bf16x8 b6 = *(const bf16x8*)(wb + 6 * 512);
        bf16x8 b7 = *(const bf16x8*)(wb + 7 * 512);
        bf16x8 a0, a1, a2, a3, a4, a5, a6, a7;
        load_a8(abase, a0, a1, a2, a3, a4, a5, a6, a7);
        MFMA(a0, b0, acc); MFMA(a1, b1, acc); MFMA(a2, b2, acc); MFMA(a3, b3, acc);
        MFMA(a4, b4, acc); MFMA(a5, b5, acc); MFMA(a6, b6, acc); MFMA(a7, b7, acc);
    }
    #pragma unroll
    for (int r = 0; r < 4; ++r)
        gsc[(wm * 16 + kq * 4 + r) * 68 + wn * 16 + rlane] = acc[r];
    lstm_epilogue(biasp, cstS, hout, gsc, brow0, lr, tid);
}

// ---------------------------------------------------------------------------
// head1: block's 16 cols, K=1024 split 4-way over wave pairs.
// ---------------------------------------------------------------------------
__device__ __forceinline__ void head1_stage(
    const short* __restrict__ ph1, const float* __restrict__ bl1,
    const short* __restrict__ h2q, const short* __restrict__ ctx,
    short* __restrict__ hidden, float* gsc, int brow0, int lr, int tid)
{
    const int wave = tid >> 6, lane = tid & 63;
    const int wm = wave & 1, kq2 = wave >> 1;
    const int rlane = lane & 15, kq = lane >> 4;
    const int arow = brow0 + wm * 16 + rlane;
    const short* src = (kq2 < 2) ? h2q : ctx;
    const int krel = (kq2 & 1) * 8;
    const short* abase = src + (size_t)arow * 512 + krel * 32 + kq * 8;
    const short* wb = ph1 + ((size_t)(lr * 32 + kq2 * 8) * 64 + lane) * 8;
    f32x4 acc = {};
    #pragma unroll
    for (int g = 0; g < 2; ++g) {
        bf16x8 b0 = *(const bf16x8*)(wb + (g * 4 + 0) * 512);
        bf16x8 b1 = *(const bf16x8*)(wb + (g * 4 + 1) * 512);
        bf16x8 b2 = *(const bf16x8*)(wb + (g * 4 + 2) * 512);
        bf16x8 b3 = *(const bf16x8*)(wb + (g * 4 + 3) * 512);
        bf16x8 a0, a1, a2, a3;
        load_a4(abase + g * 128, a0, a1, a2, a3);
        MFMA(a0, b0, acc); MFMA(a1, b1, acc); MFMA(a2, b2, acc); MFMA(a3, b3, acc);
    }
    #pragma unroll
    for (int r = 0; r < 4; ++r)
        gsc[(kq2 * 2 + wm) * 256 + (kq * 4 + r) * 16 + rlane] = acc[r];
    __syncthreads();
    {
        float s = 0.f;
        #pragma unroll
        for (int k = 0; k < 4; ++k) s += gsc[(k * 2 + (tid >> 8)) * 256 + (tid & 255)];
        int row = (tid >> 8) * 16 + ((tid >> 4) & 15);
        int col = lr * 16 + (tid & 15);
        hidden[(size_t)(brow0 + row) * 512 + col] = f2bf(fmaxf(s + bl1[col], 0.f));
    }
    __syncthreads();
}

// ---------------------------------------------------------------------------
// head2 (blocks lr 9..17): n-tile of 16 cols, K=512.
// ---------------------------------------------------------------------------
__device__ __forceinline__ void head2_stage(
    const short* __restrict__ ph2, const float* __restrict__ bl2,
    const short* __restrict__ hidden, float* __restrict__ out, int t,
    float* gsc, int brow0, int nt, int tid)
{
    const int wave = tid >> 6, lane = tid & 63;
    const int wm = wave & 1, kq4 = wave >> 1;
    const int rlane = lane & 15, kq = lane >> 4;
    const int arow = brow0 + wm * 16 + rlane;
    const short* abase = hidden + (size_t)arow * 512 + kq4 * 128 + kq * 8;
    const short* wb = ph2 + ((size_t)(nt * 16 + kq4 * 4) * 64 + lane) * 8;
    bf16x8 b0 = *(const bf16x8*)(wb + 0 * 512);
    bf16x8 b1 = *(const bf16x8*)(wb + 1 * 512);
    bf16x8 b2 = *(const bf16x8*)(wb + 2 * 512);
    bf16x8 b3 = *(const bf16x8*)(wb + 3 * 512);
    bf16x8 a0, a1, a2, a3;
    load_a4(abase, a0, a1, a2, a3);
    f32x4 acc = {};
    MFMA(a0, b0, acc); MFMA(a1, b1, acc); MFMA(a2, b2, acc); MFMA(a3, b3, acc);
    #pragma unroll
    for (int r = 0; r < 4; ++r)
        gsc[(kq4 * 2 + wm) * 256 + (kq * 4 + r) * 16 + rlane] = acc[r];
    __syncthreads();
    {
        float s = 0.f;
        #pragma unroll
        for (int k = 0; k < 4; ++k) s += gsc[(k * 2 + (tid >> 8)) * 256 + (tid & 255)];
        int row = (tid >> 8) * 16 + ((tid >> 4) & 15);
        int col = nt * 16 + (tid & 15);
        if (col < ACTN)
            out[((size_t)(brow0 + row) * TLEN + t) * ACTN + col] = s + bl2[col];
    }
}

// ---------------------------------------------------------------------------
// attention: one batch row per block; enc row held in per-thread REGISTERS.
// ---------------------------------------------------------------------------
__device__ __forceinline__ void attn_stage(
    const short* __restrict__ h2q, const bf16x8 (&encR)[8],
    const float* __restrict__ ENCP, const float* __restrict__ WaHT,
    const float* __restrict__ Wa2, const float* __restrict__ ba2v,
    short* __restrict__ ctx,
    float* h2s, float* part, float* hp, float* sl, int b, int tid)
{
    if (tid < 64) {
        bf16x8 v = load_a1(h2q + (size_t)b * 512 + tid * 8);
        #pragma unroll
        for (int i = 0; i < 8; ++i) h2s[tid * 8 + i] = bf2f(v[i]);
    }
    __syncthreads();
    if (tid < 8 * HATT) {
        int h = tid % HATT, sg = tid / HATT;
        float s = 0.f;
        for (int e = sg * 64; e < sg * 64 + 64; ++e) s += h2s[e] * WaHT[e * HATT + h];
        part[sg * HATT + h] = s;
    }
    __syncthreads();
    if (tid < HATT) {
        float s = 0.f;
        #pragma unroll
        for (int sg = 0; sg < 8; ++sg) s += part[sg * HATT + tid];
        hp[tid] = s;
    }
    __syncthreads();
    if (tid < LLEN) {
        float s = ba2v[0];
        const float* ep = ENCP + ((size_t)b * LLEN + tid) * HATT;
        #pragma unroll
        for (int h = 0; h < HATT; ++h)
            s += fmaxf(ep[h] + hp[h], 0.f) * Wa2[h];
        float v = tanhf(s);
        float m = v;
        for (int o = 32; o; o >>= 1) m = fmaxf(m, __shfl_xor(m, o));
        float e = __expf(v - m);
        float ss = e;
        for (int o = 32; o; o >>= 1) ss += __shfl_xor(ss, o);
        sl[tid] = e / ss;
    }
    __syncthreads();
    {
        float a = 0.f;
        #pragma unroll
        for (int i = 0; i < 8; ++i)
            #pragma unroll
            for (int j = 0; j < 8; ++j)
                a += sl[i * 8 + j] * bf2f(encR[i][j]);
        ctx[(size_t)b * 512 + tid] = f2bf(a);
    }
    __syncthreads();
}

// ---------------------------------------------------------------------------
// Persistent megakernel. Change vs r11 (single change, A/B-clean): barrier
// flag atomics lose the sc1 (device-scope) bit -> per the CDNA ISA they
// execute at the LOCAL XCD L2 instead of the MALL. All participants share
// one XCD, so L2 scope suffices; atomics never live in L1, and publish/poll
// serialize at the same physical L2 -> staleness-deadlock is impossible
// (unlike r9/r12's non-atomic flag ops, which could stick in L1).
// Publish: global_atomic_add slot,1 (no sc1). Poll: global_atomic_add
// slot,0 sc0 (returns current, no sc1). Data path identical to r11.
// ---------------------------------------------------------------------------
__launch_bounds__(512, 2)
__global__ void k_mega(
    const short* __restrict__ pack1, const short* __restrict__ pack2,
    const short* __restrict__ pack3, const short* __restrict__ ph1,
    const short* __restrict__ ph2,
    const float* __restrict__ b1p, const float* __restrict__ b2p,
    const float* __restrict__ b3p, const float* __restrict__ bl1,
    const float* __restrict__ bl2,
    const short* __restrict__ ET, const short* __restrict__ ENCB,
    const float* __restrict__ ENCP, const float* __restrict__ WaHT,
    const float* __restrict__ Wa2, const float* __restrict__ ba2v,
    const float* __restrict__ enc_c,
    short* __restrict__ h0a, short* __restrict__ h0b,
    short* __restrict__ h1a, short* __restrict__ h1b,
    short* __restrict__ h2a, short* __restrict__ h2b,
    short* __restrict__ ctx, short* __restrict__ hidden,
    int* __restrict__ cnt, unsigned* __restrict__ bar,
    float* __restrict__ out)
{
    __shared__ __align__(16) short wlds[65536];   // 128 KB: W2 slice
    __shared__ float gsc[2176];
    __shared__ float cst[3 * 512];
    __shared__ float h2s[512];
    __shared__ float part[8 * HATT];
    __shared__ float hp[HATT];
    __shared__ float sl[LLEN];
    __shared__ int sinfo[2];

    const int tid = threadIdx.x;
    const int wv = tid >> 6, lane = tid & 63;

    // --- runtime XCD registration (agent scope, one-time) ---
    int xcd_reg;
    asm volatile("s_getreg_b32 %0, hwreg(HW_REG_XCC_ID)" : "=s"(xcd_reg));
    if (tid == 0) {
        sinfo[0] = xcd_reg;
        sinfo[1] = __hip_atomic_fetch_add(&cnt[xcd_reg], 1,
                                          __ATOMIC_RELAXED, __HIP_MEMORY_SCOPE_AGENT);
    }
    __syncthreads();
    const int myx = sinfo[0], lr = sinfo[1];
    const int brow0 = myx * 32;

    // --- park W2 slice in LDS (one-time) ---
    {
        const bf16x8* s2v = (const bf16x8*)(pack2 + (size_t)lr * 65536);
        bf16x8* dst = (bf16x8*)wlds;
        for (int i = tid; i < 8192; i += 512)
            dst[i] = __builtin_nontemporal_load(&s2v[i]);
    }
    // --- park W1 (waves 0-3) / W3 (waves 4-7) in REGISTERS/AGPRs ---
    bf16x8 wreg[32];
    {
        const short* wsrc = (wv < 4)
            ? pack1 + ((size_t)((lr * 4 + wv) * 36 + 4) * 64 + lane) * 8
            : pack3 + ((size_t)((lr * 4 + (wv - 4)) * 32) * 64 + lane) * 8;
        #pragma unroll
        for (int i = 0; i < 32; ++i)
            wreg[i] = *(const bf16x8*)(wsrc + (size_t)i * 512);
    }
    // --- park this block's enc row in REGISTERS (col tid across l) ---
    bf16x8 encR[8];
    {
        const short* ebase = ENCB + ((size_t)(brow0 + lr) * LLEN) * 512 + tid;
        #pragma unroll
        for (int i = 0; i < 8; ++i) {
            bf16x8 v;
            #pragma unroll
            for (int j = 0; j < 8; ++j) v[j] = ebase[(size_t)(i * 8 + j) * 512];
            encR[i] = v;
        }
    }
    // --- c-state init ---
    {
        int row = tid >> 4, j = tid & 15;
        float cv = enc_c[(size_t)(brow0 + row) * 512 + lr * 16 + j];
        cst[tid] = cv; cst[512 + tid] = cv; cst[1024 + tid] = cv;
    }
    __syncthreads();

    // --- XCD-L2-scope atomic flag barrier ---
    unsigned gen = 0;
    unsigned* myslot = &bar[(myx * 32 + lr) * 16];
    unsigned* xslots = &bar[(size_t)myx * 32 * 16];
    auto gbar = [&]() {
        ++gen;
        asm volatile("s_waitcnt vmcnt(0)" ::: "memory");  // data stores acked at L2
        __syncthreads();
        if (tid == 0) {
            unsigned one = 1u;
            // L2-executed atomic publish (no sc1 -> local XCD L2)
            asm volatile("global_atomic_add %0, %1, off\n\t"
                         "s_waitcnt vmcnt(0)"
                         :: "v"(myslot), "v"(one) : "memory");
        }
        if (tid < 64) {
            for (;;) {
                unsigned v = 0xFFFFFFFFu;
                if (tid < 32) {
                    unsigned zero = 0u;
                    // L2-executed atomic read (add 0, sc0 returns current)
                    asm volatile("global_atomic_add %0, %1, %2, off sc0\n\t"
                                 "s_waitcnt vmcnt(0)"
                                 : "=&v"(v)
                                 : "v"(&xslots[tid * 16]), "v"(zero)
                                 : "memory");
                }
                if (__all(v >= gen)) break;
                __builtin_amdgcn_s_sleep(2);
            }
        }
        __syncthreads();
        // invalidate L1 so plain state loads see other blocks' L2 data (r11)
        asm volatile("buffer_inv" ::: "memory");
    };

    short* h0p[2] = { h0a, h0b };
    short* h1p[2] = { h1a, h1b };
    short* h2p[2] = { h2a, h2b };
    const int b_att = brow0 + lr;

    for (int t = 0; t < TLEN; ++t) {
        int p = t & 1, q = p ^ 1;
        // P1: LSTM1 (waves 0-3, W1 in regs)
        lstm1_reg(wreg, wv, lane, pack1, ET + (size_t)t * BSZ * EMBD,
                  ctx, h0p[p], b1p, cst, h0p[q], gsc, brow0, lr, tid);
        gbar();
        // P2: LSTM2 (all waves, W2 in LDS)
        lstm2_lds(wlds, h0p[q], h1p[p], b2p, cst + 512, h1p[q],
                  gsc, brow0, lr, tid);
        gbar();
        // P3: LSTM3 (waves 4-7, W3 in regs)
        lstm3_reg(wreg, wv, lane, h1p[q], h2p[p], b3p, cst + 1024, h2p[q],
                  gsc, brow0, lr, tid);
        gbar();
        // P4: attention + head2(t-1) on blocks 9..17
        attn_stage(h2p[q], encR, ENCP, WaHT, Wa2, ba2v, ctx,
                   h2s, part, hp, sl, b_att, tid);
        if (t > 0 && lr >= 9 && lr < 18)
            head2_stage(ph2, bl2, hidden, out, t - 1, gsc, brow0, lr - 9, tid);
        gbar();
        // P5: head1 -> hidden(t)  (synced via bars of t+1)
        head1_stage(ph1, bl1, h2p[q], ctx, hidden, gsc, brow0, lr, tid);
    }
    gbar();
    if (lr >= 9 && lr < 18)
        head2_stage(ph2, bl2, hidden, out, TLEN - 1, gsc, brow0, lr - 9, tid);
}

// ---------------------------------------------------------------------------
extern "C" void kernel_launch(void* const* d_in, const int* in_sizes, int n_in,
                              void* d_out, int out_size, void* d_ws, size_t ws_size,
                              hipStream_t stream)
{
    const int*   act   = (const int*)d_in[0];
    const float* enc   = (const float*)d_in[1];
    const float* enc_h = (const float*)d_in[2];
    const float* enc_c = (const float*)d_in[3];
    const float* embW  = (const float*)d_in[4];
    const float* Wc    = (const float*)d_in[5];
    const float* bc    = (const float*)d_in[6];
    const float* Wih1  = (const float*)d_in[7];
    const float* Whh1  = (const float*)d_in[8];
    const float* bih1  = (const float*)d_in[9];
    const float* bhh1  = (const float*)d_in[10];
    const float* Wih2  = (const float*)d_in[11];
    const float* Whh2  = (const float*)d_in[12];
    const float* bih2  = (const float*)d_in[13];
    const float* bhh2  = (const float*)d_in[14];
    const float* Wih3  = (const float*)d_in[15];
    const float* Whh3  = (const float*)d_in[16];
    const float* bih3  = (const float*)d_in[17];
    const float* bhh3  = (const float*)d_in[18];
    const float* Wa1   = (const float*)d_in[19];
    const float* ba1   = (const float*)d_in[20];
    const float* Wa2   = (const float*)d_in[21];
    const float* ba2   = (const float*)d_in[22];
    const float* Wl1   = (const float*)d_in[23];
    const float* bl1   = (const float*)d_in[24];
    const float* Wl2   = (const float*)d_in[25];
    const float* bl2   = (const float*)d_in[26];
    float* out = (float*)d_out;

    char* cur = (char*)d_ws;
    auto alloc = [&](size_t bytes) {
        char* p = cur;
        cur += (bytes + 255) & ~(size_t)255;
        return p;
    };
    int* cnt = (int*)alloc(64);
    unsigned* bar = (unsigned*)alloc(8 * 32 * 16 * 4);   // 16 KB flag slots
    short* pack1  = (short*)alloc((size_t)2048 * 1152 * 2);
    short* pack2  = (short*)alloc((size_t)2048 * 1024 * 2);
    short* pack3  = (short*)alloc((size_t)2048 * 1024 * 2);
    short* packh1 = (short*)alloc((size_t)512 * 1024 * 2);
    short* packh2 = (short*)alloc((size_t)192 * 512 * 2);
    short* ENCB   = (short*)alloc((size_t)BSZ * LLEN * 512 * 2);  // 16.8 MB
    float* W1f    = (float*)ENCB;                                  // prep alias
    float* b1p    = (float*)alloc(2048 * 4);
    float* b2p    = (float*)alloc(2048 * 4);
    float* b3p    = (float*)alloc(2048 * 4);
    float* WaHT   = (float*)alloc(512 * HATT * 4);
    float* ENCP   = (float*)alloc((size_t)BSZ * LLEN * HATT * 4);
    short* ET     = (short*)alloc((size_t)TLEN * BSZ * EMBD * 2);
    const size_t SB = (size_t)BSZ * DH;
    short* h0a = (short*)alloc(SB * 2); short* h0b = (short*)alloc(SB * 2);
    short* h1a = (short*)alloc(SB * 2); short* h1b = (short*)alloc(SB * 2);
    short* h2a = (short*)alloc(SB * 2); short* h2b = (short*)alloc(SB * 2);
    short* ctx    = (short*)alloc(SB * 2);
    short* hidden = (short*)alloc(SB * 2);

    // ---- prep ----
    hipMemsetAsync(cnt, 0, 64, stream);
    hipMemsetAsync(bar, 0, 8 * 32 * 16 * 4, stream);
    k_fold<<<dim3(32, 10), 256, 0, stream>>>(Wih1, Wc, W1f);
    k_pack1<<<1152, 256, 0, stream>>>(W1f, Whh1, pack1);
    k_encb<<<8192, 256, 0, stream>>>(enc, ENCB);      // overwrites W1f region
    k_pack23<<<1024, 256, 0, stream>>>(Wih2, Whh2, pack2);
    k_pack23<<<1024, 256, 0, stream>>>(Wih3, Whh3, pack3);
    k_packh1<<<256, 256, 0, stream>>>(Wl1, packh1);
    k_packh2<<<48, 256, 0, stream>>>(Wl2, packh2);
    k_bias<<<8, 256, 0, stream>>>(Wih1, bc, bih1, bhh1, bih2, bhh2, bih3, bhh3,
                                  b1p, b2p, b3p);
    k_tr<<<(HATT * 512 + 255) / 256, 256, 0, stream>>>(WaHT, Wa1 + 512, HATT, 512, 1024, HATT);
    k_encp<<<BSZ, 256, 0, stream>>>(enc, Wa1, ba1, ENCP);
    k_embed<<<(TLEN * BSZ * EMBD) / 256, 256, 0, stream>>>(act, embW, ET);
    k_init<<<512, 256, 0, stream>>>(enc_h, h0a, h1a, h2a, ctx);

    // ---- persistent recurrent megakernel ----
    k_mega<<<256, 512, 0, stream>>>(
        pack1, pack2, pack3, packh1, packh2,
        b1p, b2p, b3p, bl1, bl2,
        ET, ENCB, ENCP, WaHT, Wa2, ba2,
        enc_c,
        h0a, h0b, h1a, h1b, h2a, h2b,
        ctx, hidden, cnt, bar, out);
}